// Round 1
// baseline (946.250 us; speedup 1.0000x reference)
//
#include <hip/hip_runtime.h>
#include <math.h>

// Problem constants (B=2, N=1024, C=1024, H=16, D=64)
#define NSEQ   1024
#define KDIM   1024
#define TWOC   2048
#define NB     65536   // NSEQ * 64 floats per (b,h,part) plane

// ---------------------------------------------------------------------------
// Kernel 1: projection GEMM  Y = X @ W + bias, output rearranged to
// [bidx*32 + h*2 + part][n][d]  (part 0 = real cols, 1 = imag cols)
// Grid: (16, 16, 3) blocks of 256 threads, 128x128 tile, BK=8, 8x8/thread.
// ---------------------------------------------------------------------------
__global__ __launch_bounds__(256)
void proj_gemm(const float* __restrict__ X,
               const float* __restrict__ Wq, const float* __restrict__ Bq,
               const float* __restrict__ Wk, const float* __restrict__ Bk,
               const float* __restrict__ Wv, const float* __restrict__ Bv,
               float* __restrict__ Yq, float* __restrict__ Yk, float* __restrict__ Yv)
{
    const float* W; const float* bias; float* Y;
    if (blockIdx.z == 0)      { W = Wq; bias = Bq; Y = Yq; }
    else if (blockIdx.z == 1) { W = Wk; bias = Bk; Y = Yk; }
    else                      { W = Wv; bias = Bv; Y = Yv; }

    __shared__ float As[8][132];   // [k][m], padded
    __shared__ float Bs[8][132];   // [k][n], padded

    const int t  = threadIdx.x;
    const int ty = t >> 4;          // 0..15 -> row group
    const int tx = t & 15;          // 0..15 -> col group
    const int by = blockIdx.y, bx = blockIdx.x;

    float acc[8][8];
#pragma unroll
    for (int i = 0; i < 8; ++i)
#pragma unroll
        for (int j = 0; j < 8; ++j) acc[i][j] = 0.f;

    const int arow = t >> 1;         // 0..127
    const int akq  = (t & 1) * 4;    // 0 or 4
    const float* Xp = X + (size_t)(by * 128 + arow) * KDIM + akq;

    const int brow = t >> 5;         // 0..7
    const int bn4  = (t & 31) * 4;   // 0..124
    const float* Wp = W + (size_t)brow * TWOC + bx * 128 + bn4;

    for (int k0 = 0; k0 < KDIM; k0 += 8) {
        float4 av = *(const float4*)(Xp + k0);
        float4 bv = *(const float4*)(Wp + (size_t)k0 * TWOC);
        __syncthreads();
        As[akq + 0][arow] = av.x;
        As[akq + 1][arow] = av.y;
        As[akq + 2][arow] = av.z;
        As[akq + 3][arow] = av.w;
        *(float4*)&Bs[brow][bn4] = bv;
        __syncthreads();
#pragma unroll
        for (int kk = 0; kk < 8; ++kk) {
            float a[8], b[8];
            float4 a0 = *(float4*)&As[kk][ty * 8];
            float4 a1 = *(float4*)&As[kk][ty * 8 + 4];
            float4 b0 = *(float4*)&Bs[kk][tx * 8];
            float4 b1 = *(float4*)&Bs[kk][tx * 8 + 4];
            a[0]=a0.x; a[1]=a0.y; a[2]=a0.z; a[3]=a0.w;
            a[4]=a1.x; a[5]=a1.y; a[6]=a1.z; a[7]=a1.w;
            b[0]=b0.x; b[1]=b0.y; b[2]=b0.z; b[3]=b0.w;
            b[4]=b1.x; b[5]=b1.y; b[6]=b1.z; b[7]=b1.w;
#pragma unroll
            for (int i = 0; i < 8; ++i)
#pragma unroll
                for (int j = 0; j < 8; ++j)
                    acc[i][j] += a[i] * b[j];
        }
    }

    // Epilogue: +bias, store rearranged [bidx*32 + h*2 + part][n][d]
    const int col0 = bx * 128 + tx * 8;
    const int h    = col0 >> 7;
    const int part = (col0 >> 6) & 1;
    const int d0   = col0 & 63;
    float bb8[8];
#pragma unroll
    for (int j = 0; j < 8; ++j) bb8[j] = bias[col0 + j];

#pragma unroll
    for (int i = 0; i < 8; ++i) {
        const int grow = by * 128 + ty * 8 + i;   // b*N + n
        const int bidx = grow >> 10;
        const int n    = grow & 1023;
        float* dst = Y + (size_t)(bidx * 32 + h * 2 + part) * NB + n * 64 + d0;
        float4 r0, r1;
        r0.x = acc[i][0] + bb8[0]; r0.y = acc[i][1] + bb8[1];
        r0.z = acc[i][2] + bb8[2]; r0.w = acc[i][3] + bb8[3];
        r1.x = acc[i][4] + bb8[4]; r1.y = acc[i][5] + bb8[5];
        r1.z = acc[i][6] + bb8[6]; r1.w = acc[i][7] + bb8[7];
        *(float4*)dst       = r0;
        *(float4*)(dst + 4) = r1;
    }
}

// ---------------------------------------------------------------------------
// Kernel 2: in-place LayerNorm (+gamma/beta) + ReLU over the 2048 channels of
// each (b,n) row, reading the rearranged layout. Grid (2048, 3), 256 threads.
// ---------------------------------------------------------------------------
__global__ __launch_bounds__(256)
void ln_relu(float* __restrict__ Yq, float* __restrict__ Yk, float* __restrict__ Yv,
             const float* __restrict__ Gq, const float* __restrict__ BTq,
             const float* __restrict__ Gk, const float* __restrict__ BTk,
             const float* __restrict__ Gv, const float* __restrict__ BTv)
{
    float* Y; const float* G; const float* Bt;
    if (blockIdx.y == 0)      { Y = Yq; G = Gq; Bt = BTq; }
    else if (blockIdx.y == 1) { Y = Yk; G = Gk; Bt = BTk; }
    else                      { Y = Yv; G = Gv; Bt = BTv; }

    const int r    = blockIdx.x;     // 0..2047 = b*N + n
    const int bidx = r >> 10;
    const int n    = r & 1023;
    const int t    = threadIdx.x;
    const int e0   = t * 8;          // channel index of first element
    const int chunk = e0 >> 6;       // = h*2+part
    const int d     = e0 & 63;

    float* p = Y + (size_t)(bidx * 32 + chunk) * NB + n * 64 + d;
    float4 v0 = *(float4*)p;
    float4 v1 = *(float4*)(p + 4);
    float xv[8] = {v0.x, v0.y, v0.z, v0.w, v1.x, v1.y, v1.z, v1.w};

    __shared__ float red[8];
    float s = 0.f;
#pragma unroll
    for (int j = 0; j < 8; ++j) s += xv[j];
#pragma unroll
    for (int off = 32; off > 0; off >>= 1) s += __shfl_down(s, off);
    const int lane = t & 63, wid = t >> 6;
    if (lane == 0) red[wid] = s;
    __syncthreads();
    const float mean = (red[0] + red[1] + red[2] + red[3]) * (1.f / 2048.f);
    __syncthreads();

    float sq = 0.f;
#pragma unroll
    for (int j = 0; j < 8; ++j) { float dx = xv[j] - mean; sq += dx * dx; }
#pragma unroll
    for (int off = 32; off > 0; off >>= 1) sq += __shfl_down(sq, off);
    if (lane == 0) red[wid] = sq;
    __syncthreads();
    const float var  = (red[0] + red[1] + red[2] + red[3]) * (1.f / 2048.f);
    const float rstd = 1.f / sqrtf(var + 1e-5f);

    float4 o0, o1;
    float y0 = fmaxf((xv[0]-mean)*rstd*G[e0+0] + Bt[e0+0], 0.f);
    float y1 = fmaxf((xv[1]-mean)*rstd*G[e0+1] + Bt[e0+1], 0.f);
    float y2 = fmaxf((xv[2]-mean)*rstd*G[e0+2] + Bt[e0+2], 0.f);
    float y3 = fmaxf((xv[3]-mean)*rstd*G[e0+3] + Bt[e0+3], 0.f);
    float y4 = fmaxf((xv[4]-mean)*rstd*G[e0+4] + Bt[e0+4], 0.f);
    float y5 = fmaxf((xv[5]-mean)*rstd*G[e0+5] + Bt[e0+5], 0.f);
    float y6 = fmaxf((xv[6]-mean)*rstd*G[e0+6] + Bt[e0+6], 0.f);
    float y7 = fmaxf((xv[7]-mean)*rstd*G[e0+7] + Bt[e0+7], 0.f);
    o0.x=y0; o0.y=y1; o0.z=y2; o0.w=y3;
    o1.x=y4; o1.y=y5; o1.z=y6; o1.w=y7;
    *(float4*)p       = o0;
    *(float4*)(p + 4) = o1;
}

// ---------------------------------------------------------------------------
// Kernel 3: flash-style attention. Grid (B*H=32, N/32=32), 256 threads.
// Thread (tq,tk) owns queries {tq, tq+16}, key cols {tk, tk+16} in S-phase
// and output cols tk*8..tk*8+7 in O-phase (same query rows -> m/l/scale stay
// in registers, replicated across the 16-lane row group).
// ---------------------------------------------------------------------------
__global__ __launch_bounds__(256)
void attn(const float* __restrict__ Qb, const float* __restrict__ Kb,
          const float* __restrict__ Vb,
          const float* __restrict__ amp_mix, const float* __restrict__ phase_mix,
          float* __restrict__ Out)
{
    const int bh   = blockIdx.x;     // b*16 + h
    const int qt   = blockIdx.y;     // 0..31
    const int bidx = bh >> 4;
    const int h    = bh & 15;

    __shared__ float Qr[32][68], Qi[32][68];
    __shared__ float Kr[32][68], Ki[32][68];
    __shared__ float Vr[32][68], Vi[32][68];
    __shared__ float P[32][36];

    const int t  = threadIdx.x;
    const int tq = t >> 4, tk = t & 15;
    const int e  = t * 8, rr = e >> 6, dd = e & 63;

    // Load Q tiles (each part: contiguous 2048-float chunk)
    {
        const float* qr_g = Qb + (size_t)(bh * 2 + 0) * NB + qt * 2048;
        const float* qi_g = Qb + (size_t)(bh * 2 + 1) * NB + qt * 2048;
        float4 a0 = *(const float4*)(qr_g + e);
        float4 a1 = *(const float4*)(qr_g + e + 4);
        float4 b0 = *(const float4*)(qi_g + e);
        float4 b1 = *(const float4*)(qi_g + e + 4);
        *(float4*)&Qr[rr][dd]     = a0;
        *(float4*)&Qr[rr][dd + 4] = a1;
        *(float4*)&Qi[rr][dd]     = b0;
        *(float4*)&Qi[rr][dd + 4] = b1;
    }

    const float amix = amp_mix[h], pmix = phase_mix[h];
    const int q0 = tq, q1 = tq + 16;
    const int k0i = tk, k1i = tk + 16;

    float m0 = -INFINITY, m1 = -INFINITY, l0 = 0.f, l1 = 0.f;
    float o0[8], o1[8];
#pragma unroll
    for (int j = 0; j < 8; ++j) { o0[j] = 0.f; o1[j] = 0.f; }

    const float* kr_g = Kb + (size_t)(bh * 2 + 0) * NB;
    const float* ki_g = Kb + (size_t)(bh * 2 + 1) * NB;
    const float* vr_g = Vb + (size_t)(bh * 2 + 0) * NB;
    const float* vi_g = Vb + (size_t)(bh * 2 + 1) * NB;

    for (int kt = 0; kt < 32; ++kt) {
        const int go = kt * 2048 + e;
        float4 gkr0 = *(const float4*)(kr_g + go), gkr1 = *(const float4*)(kr_g + go + 4);
        float4 gki0 = *(const float4*)(ki_g + go), gki1 = *(const float4*)(ki_g + go + 4);
        float4 gvr0 = *(const float4*)(vr_g + go), gvr1 = *(const float4*)(vr_g + go + 4);
        float4 gvi0 = *(const float4*)(vi_g + go), gvi1 = *(const float4*)(vi_g + go + 4);
        __syncthreads();   // prior O-phase reads of K/V/P done
        *(float4*)&Kr[rr][dd] = gkr0; *(float4*)&Kr[rr][dd + 4] = gkr1;
        *(float4*)&Ki[rr][dd] = gki0; *(float4*)&Ki[rr][dd + 4] = gki1;
        *(float4*)&Vr[rr][dd] = gvr0; *(float4*)&Vr[rr][dd + 4] = gvr1;
        *(float4*)&Vi[rr][dd] = gvi0; *(float4*)&Vi[rr][dd + 4] = gvi1;
        __syncthreads();

        // ----- S phase: amp/phase raw dots for 2x2 (q,k) pairs -----
        float ar00=0, ar01=0, ar10=0, ar11=0;
        float pr00=0, pr01=0, pr10=0, pr11=0;
#pragma unroll 4
        for (int d4 = 0; d4 < 64; d4 += 4) {
            float qr_[2][4], qi_[2][4], kr_[2][4], ki_[2][4];
            *(float4*)qr_[0] = *(float4*)&Qr[q0][d4];
            *(float4*)qr_[1] = *(float4*)&Qr[q1][d4];
            *(float4*)qi_[0] = *(float4*)&Qi[q0][d4];
            *(float4*)qi_[1] = *(float4*)&Qi[q1][d4];
            *(float4*)kr_[0] = *(float4*)&Kr[k0i][d4];
            *(float4*)kr_[1] = *(float4*)&Kr[k1i][d4];
            *(float4*)ki_[0] = *(float4*)&Ki[k0i][d4];
            *(float4*)ki_[1] = *(float4*)&Ki[k1i][d4];
#pragma unroll
            for (int x = 0; x < 4; ++x) {
                ar00 += qr_[0][x]*kr_[0][x] - qi_[0][x]*ki_[0][x];
                pr00 += qr_[0][x]*ki_[0][x] + qi_[0][x]*kr_[0][x];
                ar01 += qr_[0][x]*kr_[1][x] - qi_[0][x]*ki_[1][x];
                pr01 += qr_[0][x]*ki_[1][x] + qi_[0][x]*kr_[1][x];
                ar10 += qr_[1][x]*kr_[0][x] - qi_[1][x]*ki_[0][x];
                pr10 += qr_[1][x]*ki_[0][x] + qi_[1][x]*kr_[0][x];
                ar11 += qr_[1][x]*kr_[1][x] - qi_[1][x]*ki_[1][x];
                pr11 += qr_[1][x]*ki_[1][x] + qi_[1][x]*kr_[1][x];
            }
        }

        float sc[2][2];
        {
            float ar[4] = {ar00, ar01, ar10, ar11};
            float pr[4] = {pr00, pr01, pr10, pr11};
#pragma unroll
            for (int z = 0; z < 4; ++z) {
                float amp = ar[z] * amix;
                float ph  = pr[z] * pmix;
                float sn, cs;
                sincosf(ph, &sn, &cs);
                float g1  = amp * sn;
                float sig = 1.f / (1.f + expf(-g1));
                sc[z >> 1][z & 1] = amp * cs * sig;
            }
        }

        // ----- online softmax (per-row state replicated across 16 lanes) -----
        float rmax0 = fmaxf(sc[0][0], sc[0][1]);
        float rmax1 = fmaxf(sc[1][0], sc[1][1]);
#pragma unroll
        for (int ofs = 1; ofs < 16; ofs <<= 1) {
            rmax0 = fmaxf(rmax0, __shfl_xor(rmax0, ofs));
            rmax1 = fmaxf(rmax1, __shfl_xor(rmax1, ofs));
        }
        const float mn0 = fmaxf(m0, rmax0);
        const float mn1 = fmaxf(m1, rmax1);
        const float scale0 = expf(m0 - mn0);
        const float scale1 = expf(m1 - mn1);
        const float p00 = expf(sc[0][0] - mn0), p01 = expf(sc[0][1] - mn0);
        const float p10 = expf(sc[1][0] - mn1), p11 = expf(sc[1][1] - mn1);
        float rs0 = p00 + p01, rs1 = p10 + p11;
#pragma unroll
        for (int ofs = 1; ofs < 16; ofs <<= 1) {
            rs0 += __shfl_xor(rs0, ofs);
            rs1 += __shfl_xor(rs1, ofs);
        }
        l0 = l0 * scale0 + rs0;  m0 = mn0;
        l1 = l1 * scale1 + rs1;  m1 = mn1;

        P[q0][tk]      = p00;  P[q0][tk + 16] = p01;
        P[q1][tk]      = p10;  P[q1][tk + 16] = p11;
        __syncthreads();

        // ----- O phase: O[q][col] += P[q][k] * V[k][col], col = tk*8..+7 -----
        const float (*Vsel)[68] = (tk < 8) ? Vr : Vi;
        const int vd0 = (tk * 8) & 63;
#pragma unroll
        for (int j = 0; j < 8; ++j) { o0[j] *= scale0; o1[j] *= scale1; }
#pragma unroll 8
        for (int kk = 0; kk < 32; ++kk) {
            const float pa = P[q0][kk];
            const float pb = P[q1][kk];
            float4 va = *(float4*)&Vsel[kk][vd0];
            float4 vb4 = *(float4*)&Vsel[kk][vd0 + 4];
            float vv[8] = {va.x, va.y, va.z, va.w, vb4.x, vb4.y, vb4.z, vb4.w};
#pragma unroll
            for (int j = 0; j < 8; ++j) {
                o0[j] += pa * vv[j];
                o1[j] += pb * vv[j];
            }
        }
    }

    // ----- write output: out[b][n][h*128 + tk*8 .. +7] -----
    const float inv0 = 1.f / l0, inv1 = 1.f / l1;
    const int n0 = qt * 32 + q0, n1 = qt * 32 + q1;
    float* dst0 = Out + (size_t)(bidx * NSEQ + n0) * TWOC + h * 128 + tk * 8;
    float* dst1 = Out + (size_t)(bidx * NSEQ + n1) * TWOC + h * 128 + tk * 8;
    float4 w0, w1;
    w0.x=o0[0]*inv0; w0.y=o0[1]*inv0; w0.z=o0[2]*inv0; w0.w=o0[3]*inv0;
    w1.x=o0[4]*inv0; w1.y=o0[5]*inv0; w1.z=o0[6]*inv0; w1.w=o0[7]*inv0;
    *(float4*)dst0 = w0; *(float4*)(dst0 + 4) = w1;
    w0.x=o1[0]*inv1; w0.y=o1[1]*inv1; w0.z=o1[2]*inv1; w0.w=o1[3]*inv1;
    w1.x=o1[4]*inv1; w1.y=o1[5]*inv1; w1.z=o1[6]*inv1; w1.w=o1[7]*inv1;
    *(float4*)dst1 = w0; *(float4*)(dst1 + 4) = w1;
}

// ---------------------------------------------------------------------------
extern "C" void kernel_launch(void* const* d_in, const int* in_sizes, int n_in,
                              void* d_out, int out_size, void* d_ws, size_t ws_size,
                              hipStream_t stream) {
    (void)in_sizes; (void)n_in; (void)out_size; (void)ws_size;
    const float* x      = (const float*)d_in[0];
    const float* q_w    = (const float*)d_in[1];
    const float* q_b    = (const float*)d_in[2];
    const float* q_g    = (const float*)d_in[3];
    const float* q_beta = (const float*)d_in[4];
    const float* k_w    = (const float*)d_in[5];
    const float* k_b    = (const float*)d_in[6];
    const float* k_g    = (const float*)d_in[7];
    const float* k_beta = (const float*)d_in[8];
    const float* v_w    = (const float*)d_in[9];
    const float* v_b    = (const float*)d_in[10];
    const float* v_g    = (const float*)d_in[11];
    const float* v_beta = (const float*)d_in[12];
    const float* amp_mix   = (const float*)d_in[13];
    const float* phase_mix = (const float*)d_in[14];

    // Workspace: 3 buffers of 2048*2048 f32 = 16 MB each (48 MB total)
    float* ws   = (float*)d_ws;
    float* qbuf = ws;
    float* kbuf = ws + (size_t)4194304;
    float* vbuf = ws + (size_t)8388608;

    proj_gemm<<<dim3(16, 16, 3), 256, 0, stream>>>(
        x, q_w, q_b, k_w, k_b, v_w, v_b, qbuf, kbuf, vbuf);
    ln_relu<<<dim3(2048, 3), 256, 0, stream>>>(
        qbuf, kbuf, vbuf, q_g, q_beta, k_g, k_beta, v_g, v_beta);
    attn<<<dim3(32, 32), 256, 0, stream>>>(
        qbuf, kbuf, vbuf, amp_mix, phase_mix, (float*)d_out);
}

// Round 2
// 653.900 us; speedup vs baseline: 1.4471x; 1.4471x over previous
//
#include <hip/hip_runtime.h>
#include <math.h>

// Problem constants (B=2, N=1024, C=1024, H=16, D=64)
#define NSEQ   1024
#define KDIM   1024
#define TWOC   2048
#define NB     65536   // NSEQ * 64 floats per (b,h,part) plane

typedef float  f32x4  __attribute__((ext_vector_type(4)));
typedef short  short8 __attribute__((ext_vector_type(8)));
typedef __bf16 bf16x8 __attribute__((ext_vector_type(8)));

// Panel geometry: 128 rows x 32 k bf16, padded to 40 bf16/row (80 B) so that
// frag ds_read_b128 (row stride 80B -> bank step 20) lands ~conflict-free.
#define PANROW   40
#define PANHALF  10240    // bytes per panel half (128*40*2)
#define PANPAIR  20480    // hi + lo
#define NPAN_K   32       // 1024 / 32
#define WPAN_Z_BYTES 10485760u  // 16*32*PANPAIR

__device__ __forceinline__ unsigned short bf16_rne(float x) {
    unsigned int u = __float_as_uint(x);
    u += 0x7fffu + ((u >> 16) & 1u);
    return (unsigned short)(u >> 16);
}

__device__ __forceinline__ void gload_lds16(const void* g, void* l) {
    __builtin_amdgcn_global_load_lds(
        (const __attribute__((address_space(1))) unsigned int*)g,
        (__attribute__((address_space(3))) unsigned int*)l, 16, 0, 0);
}

// ---------------------------------------------------------------------------
// split_x: X[2048][1024] f32 -> hi/lo bf16 panels [mb][ks] of 128x32 (padded).
// ---------------------------------------------------------------------------
__global__ __launch_bounds__(256)
void split_x(const float* __restrict__ X, unsigned short* __restrict__ Xpan)
{
    const int c  = blockIdx.x * 256 + threadIdx.x;   // 262144 chunks
    const int m  = c >> 7;
    const int k0 = (c & 127) << 3;
    f32x4 v0 = *(const f32x4*)(X + (size_t)m * KDIM + k0);
    f32x4 v1 = *(const f32x4*)(X + (size_t)m * KDIM + k0 + 4);
    float xv[8] = {v0[0],v0[1],v0[2],v0[3],v1[0],v1[1],v1[2],v1[3]};
    short8 h8, l8;
#pragma unroll
    for (int j = 0; j < 8; ++j) {
        unsigned short h = bf16_rne(xv[j]);
        float hf = __uint_as_float((unsigned int)h << 16);
        unsigned short lo = bf16_rne(xv[j] - hf);
        h8[j] = (short)h; l8[j] = (short)lo;
    }
    const int mb = m >> 7, ml = m & 127, ks = k0 >> 5, kl = k0 & 31;
    char* base = (char*)Xpan + (size_t)(mb * NPAN_K + ks) * PANPAIR + ml * 80 + kl * 2;
    *(short8*)base = h8;
    *(short8*)(base + PANHALF) = l8;
}

// ---------------------------------------------------------------------------
// split_w: W[1024][2048] f32 -> transposed hi/lo bf16 panels [nb][ks], row=n.
// LDS-tiled transpose (64k x 32n tiles). Grid (64, 16, 3).
// ---------------------------------------------------------------------------
__global__ __launch_bounds__(256)
void split_w(const float* __restrict__ Wq, const float* __restrict__ Wk,
             const float* __restrict__ Wv, unsigned short* __restrict__ Wpan)
{
    const int z = blockIdx.z;
    const float* W = (z == 0) ? Wq : (z == 1) ? Wk : Wv;
    char* pan = (char*)Wpan + (size_t)z * WPAN_Z_BYTES;

    __shared__ __align__(16) float T[64][36];
    const int t  = threadIdx.x;
    const int nt = blockIdx.x;   // 0..63 (n tiles of 32)
    const int kt = blockIdx.y;   // 0..15 (k tiles of 64)
    const int kk = t >> 3, cc = (t & 7) * 4;
#pragma unroll
    for (int i = 0; i < 2; ++i) {
        int kr = kk + i * 32;
        *(f32x4*)&T[kr][cc] = *(const f32x4*)(W + (size_t)(kt * 64 + kr) * TWOC + nt * 32 + cc);
    }
    __syncthreads();
    const int n_i = t & 31, kc = t >> 5;     // kc 0..7
    const int k0 = kc * 8;
    short8 h8, l8;
#pragma unroll
    for (int x = 0; x < 8; ++x) {
        float xv = T[k0 + x][n_i];
        unsigned short h = bf16_rne(xv);
        float hf = __uint_as_float((unsigned int)h << 16);
        unsigned short lo = bf16_rne(xv - hf);
        h8[x] = (short)h; l8[x] = (short)lo;
    }
    const int n_g = nt * 32 + n_i;
    const int nbk = n_g >> 7, nl = n_g & 127;
    const int k_g = kt * 64 + k0;
    const int ks = k_g >> 5, kl = k_g & 31;
    char* base = pan + (size_t)(nbk * NPAN_K + ks) * PANPAIR + nl * 80 + kl * 2;
    *(short8*)base = h8;
    *(short8*)(base + PANHALF) = l8;
}

// ---------------------------------------------------------------------------
// mfma_gemm: Y = X @ W + bias via split-bf16 (hi/lo) MFMA, 128x128 tile,
// 4 waves of 64x64, 16x16x32 bf16 MFMA, global_load_lds staging.
// Output rearranged to [bidx*32 + h*2 + part][n][d]. Grid (16, 16, 3).
// ---------------------------------------------------------------------------
__global__ __launch_bounds__(256)
void mfma_gemm(const unsigned short* __restrict__ Xpan,
               const unsigned short* __restrict__ Wpan,
               const float* __restrict__ Bq, const float* __restrict__ Bk,
               const float* __restrict__ Bv,
               float* __restrict__ Yq, float* __restrict__ Yk, float* __restrict__ Yv)
{
    __shared__ __align__(16) char AB[40960];   // [A hi|lo 20480][B hi|lo 20480]
    const int t = threadIdx.x, l = t & 63, w = t >> 6;
    const int wm = w >> 1, wn = w & 1;
    const int nb = blockIdx.x, mb = blockIdx.y, z = blockIdx.z;
    const char* Apan = (const char*)Xpan + (size_t)mb * NPAN_K * PANPAIR;
    const char* Bpan = (const char*)Wpan + (size_t)z * WPAN_Z_BYTES
                                        + (size_t)nb * NPAN_K * PANPAIR;
    const float* bias = (z == 0) ? Bq : (z == 1) ? Bk : Bv;
    float* Y = (z == 0) ? Yq : (z == 1) ? Yk : Yv;

    f32x4 acc[4][4];
#pragma unroll
    for (int i = 0; i < 4; ++i)
#pragma unroll
        for (int j = 0; j < 4; ++j) acc[i][j] = (f32x4){0.f, 0.f, 0.f, 0.f};

    {   // prologue: stage ks=0 (40 KB)
#pragma unroll
        for (int r = 0; r < 5; ++r) {
            int off = r * 4096 + t * 16;
            gload_lds16(Apan + off, AB + off);
            gload_lds16(Bpan + off, AB + 20480 + off);
        }
    }
    const int lg  = (l >> 4) * 16;   // k-group byte offset within row
    const int l15 = l & 15;

    for (int ks = 0; ks < 32; ++ks) {
        __syncthreads();   // staged data ready (drains vmcnt)
        short8 ahi[4], alo[4];
#pragma unroll
        for (int fi = 0; fi < 4; ++fi) {
            int row = wm * 64 + fi * 16 + l15;
            ahi[fi] = *(const short8*)(AB + row * 80 + lg);
            alo[fi] = *(const short8*)(AB + PANHALF + row * 80 + lg);
        }
#pragma unroll
        for (int fj = 0; fj < 4; ++fj) {
            int rn = wn * 64 + fj * 16 + l15;
            short8 bh = *(const short8*)(AB + 20480 + rn * 80 + lg);
            short8 bl = *(const short8*)(AB + 30720 + rn * 80 + lg);
            bf16x8 bhv = __builtin_bit_cast(bf16x8, bh);
            bf16x8 blv = __builtin_bit_cast(bf16x8, bl);
#pragma unroll
            for (int fi = 0; fi < 4; ++fi) {
                bf16x8 ahv = __builtin_bit_cast(bf16x8, ahi[fi]);
                bf16x8 alv = __builtin_bit_cast(bf16x8, alo[fi]);
                acc[fi][fj] = __builtin_amdgcn_mfma_f32_16x16x32_bf16(ahv, bhv, acc[fi][fj], 0, 0, 0);
                acc[fi][fj] = __builtin_amdgcn_mfma_f32_16x16x32_bf16(ahv, blv, acc[fi][fj], 0, 0, 0);
                acc[fi][fj] = __builtin_amdgcn_mfma_f32_16x16x32_bf16(alv, bhv, acc[fi][fj], 0, 0, 0);
            }
        }
        __syncthreads();   // all waves done reading LDS
        if (ks < 31) {
            const char* ga = Apan + (size_t)(ks + 1) * PANPAIR;
            const char* gb = Bpan + (size_t)(ks + 1) * PANPAIR;
#pragma unroll
            for (int r = 0; r < 5; ++r) {
                int off = r * 4096 + t * 16;
                gload_lds16(ga + off, AB + off);
                gload_lds16(gb + off, AB + 20480 + off);
            }
        }
    }

    // epilogue: +bias, rearranged store. C/D: col = l&15, row = 4*(l>>4)+r.
#pragma unroll
    for (int fj = 0; fj < 4; ++fj) {
        int ccol = nb * 128 + wn * 64 + fj * 16 + l15;
        float bb = bias[ccol];
        int hh = ccol >> 7, pp = (ccol >> 6) & 1, d0 = ccol & 63;
        float* ybase = Y + (size_t)(hh * 2 + pp) * NB + d0;
#pragma unroll
        for (int fi = 0; fi < 4; ++fi) {
            int mb4 = mb * 128 + wm * 64 + fi * 16 + (l >> 4) * 4;
#pragma unroll
            for (int r = 0; r < 4; ++r) {
                int mg = mb4 + r;
                int bidx = mg >> 10, n = mg & 1023;
                ybase[(size_t)(bidx * 32) * NB + n * 64] = acc[fi][fj][r] + bb;
            }
        }
    }
}

// ---------------------------------------------------------------------------
// ln_relu: unchanged from round 1 (passed; ~16 us, memory-bound).
// ---------------------------------------------------------------------------
__global__ __launch_bounds__(256)
void ln_relu(float* __restrict__ Yq, float* __restrict__ Yk, float* __restrict__ Yv,
             const float* __restrict__ Gq, const float* __restrict__ BTq,
             const float* __restrict__ Gk, const float* __restrict__ BTk,
             const float* __restrict__ Gv, const float* __restrict__ BTv)
{
    float* Y; const float* G; const float* Bt;
    if (blockIdx.y == 0)      { Y = Yq; G = Gq; Bt = BTq; }
    else if (blockIdx.y == 1) { Y = Yk; G = Gk; Bt = BTk; }
    else                      { Y = Yv; G = Gv; Bt = BTv; }

    const int r    = blockIdx.x;
    const int bidx = r >> 10;
    const int n    = r & 1023;
    const int t    = threadIdx.x;
    const int e0   = t * 8;
    const int chunk = e0 >> 6;
    const int d     = e0 & 63;

    float* p = Y + (size_t)(bidx * 32 + chunk) * NB + n * 64 + d;
    f32x4 v0 = *(f32x4*)p;
    f32x4 v1 = *(f32x4*)(p + 4);
    float xv[8] = {v0[0],v0[1],v0[2],v0[3],v1[0],v1[1],v1[2],v1[3]};

    __shared__ float red[8];
    float s = 0.f;
#pragma unroll
    for (int j = 0; j < 8; ++j) s += xv[j];
#pragma unroll
    for (int off = 32; off > 0; off >>= 1) s += __shfl_down(s, off);
    const int lane = t & 63, wid = t >> 6;
    if (lane == 0) red[wid] = s;
    __syncthreads();
    const float mean = (red[0] + red[1] + red[2] + red[3]) * (1.f / 2048.f);
    __syncthreads();

    float sq = 0.f;
#pragma unroll
    for (int j = 0; j < 8; ++j) { float dx = xv[j] - mean; sq += dx * dx; }
#pragma unroll
    for (int off = 32; off > 0; off >>= 1) sq += __shfl_down(sq, off);
    if (lane == 0) red[wid] = sq;
    __syncthreads();
    const float var  = (red[0] + red[1] + red[2] + red[3]) * (1.f / 2048.f);
    const float rstd = 1.f / sqrtf(var + 1e-5f);

    f32x4 o0, o1;
#pragma unroll
    for (int j = 0; j < 4; ++j) o0[j] = fmaxf((xv[j]   - mean) * rstd * G[e0+j]   + Bt[e0+j],   0.f);
#pragma unroll
    for (int j = 0; j < 4; ++j) o1[j] = fmaxf((xv[j+4] - mean) * rstd * G[e0+4+j] + Bt[e0+4+j], 0.f);
    *(f32x4*)p       = o0;
    *(f32x4*)(p + 4) = o1;
}

// ---------------------------------------------------------------------------
// attn: flash-style, fp32. Grid (32 bh, 32 qtiles), 256 threads.
// TQ=32, TK=64. Thread (tq8 = t>>5, tk = t&31): 4 q-rows x 2 k-cols in S,
// 4 q-rows x 4 out-cols in O. K/V time-share one swizzled LDS buffer.
// LDS swizzle: 16B slot s at (s ^ (row&15)) within [64][64] f32 rows.
// ---------------------------------------------------------------------------
__global__ __launch_bounds__(256)
void attn(const float* __restrict__ Qb, const float* __restrict__ Kb,
          const float* __restrict__ Vb,
          const float* __restrict__ amp_mix, const float* __restrict__ phase_mix,
          float* __restrict__ Out)
{
    const int bh   = blockIdx.x;
    const int qt   = blockIdx.y;
    const int bidx = bh >> 4;
    const int h    = bh & 15;

    __shared__ __align__(16) float Qr[32][68], Qi[32][68];
    __shared__ __align__(16) float KVr[64 * 64], KVi[64 * 64];
    __shared__ __align__(16) float P[32][72];

    const int t   = threadIdx.x;
    const int tq8 = t >> 5, tk = t & 31;
    const int e   = t * 8, rr = e >> 6, dd = e & 63;

    {   // load Q tile (rows qt*32..+31)
        const float* qr_g = Qb + (size_t)(bh * 2) * NB + qt * 2048;
        const float* qi_g = qr_g + NB;
        *(f32x4*)&Qr[rr][dd]     = *(const f32x4*)(qr_g + e);
        *(f32x4*)&Qr[rr][dd + 4] = *(const f32x4*)(qr_g + e + 4);
        *(f32x4*)&Qi[rr][dd]     = *(const f32x4*)(qi_g + e);
        *(f32x4*)&Qi[rr][dd + 4] = *(const f32x4*)(qi_g + e + 4);
    }

    const float amix = amp_mix[h], pmix = phase_mix[h];
    float m_[4], l_[4], sc_[4];
    f32x4 o_[4];
#pragma unroll
    for (int i = 0; i < 4; ++i) { m_[i] = -1e30f; l_[i] = 0.f; o_[i] = (f32x4){0.f,0.f,0.f,0.f}; }

    const float* kr_g = Kb + (size_t)(bh * 2) * NB;
    const float* ki_g = kr_g + NB;
    const float* vr_g = Vb + (size_t)(bh * 2) * NB;
    const float* vi_g = vr_g + NB;

    const int sw_r  = rr & 15;           // staging swizzle params
    const int s0    = dd >> 2;           // even

    for (int kt = 0; kt < 16; ++kt) {
        const int go = kt * 4096 + e;
        // prefetch K into regs (overlaps previous O-phase)
        f32x4 ka0 = *(const f32x4*)(kr_g + go),        ka1 = *(const f32x4*)(kr_g + go + 4);
        f32x4 ka2 = *(const f32x4*)(kr_g + go + 2048), ka3 = *(const f32x4*)(kr_g + go + 2052);
        f32x4 kb0 = *(const f32x4*)(ki_g + go),        kb1 = *(const f32x4*)(ki_g + go + 4);
        f32x4 kb2 = *(const f32x4*)(ki_g + go + 2048), kb3 = *(const f32x4*)(ki_g + go + 2052);
        __syncthreads();   // (A) previous O-phase done with V
        {
            int r0 = rr, r1 = rr + 32;
            *(f32x4*)&KVr[r0 * 64 + (((s0    ) ^ sw_r) << 2)] = ka0;
            *(f32x4*)&KVr[r0 * 64 + (((s0 + 1) ^ sw_r) << 2)] = ka1;
            *(f32x4*)&KVr[r1 * 64 + (((s0    ) ^ sw_r) << 2)] = ka2;
            *(f32x4*)&KVr[r1 * 64 + (((s0 + 1) ^ sw_r) << 2)] = ka3;
            *(f32x4*)&KVi[r0 * 64 + (((s0    ) ^ sw_r) << 2)] = kb0;
            *(f32x4*)&KVi[r0 * 64 + (((s0 + 1) ^ sw_r) << 2)] = kb1;
            *(f32x4*)&KVi[r1 * 64 + (((s0    ) ^ sw_r) << 2)] = kb2;
            *(f32x4*)&KVi[r1 * 64 + (((s0 + 1) ^ sw_r) << 2)] = kb3;
        }
        __syncthreads();   // (B) K ready

        // ----- S phase: 4q x 2k raw dots -----
        float ar[4][2], pr[4][2];
#pragma unroll
        for (int i = 0; i < 4; ++i) { ar[i][0]=ar[i][1]=pr[i][0]=pr[i][1]=0.f; }
        const int tks = tk & 15;
#pragma unroll 4
        for (int d4 = 0; d4 < 64; d4 += 4) {
            const int s = d4 >> 2;
            f32x4 kr0 = *(const f32x4*)&KVr[ tk       * 64 + ((s ^ tks) << 2)];
            f32x4 kr1 = *(const f32x4*)&KVr[(tk + 32) * 64 + ((s ^ tks) << 2)];
            f32x4 ki0 = *(const f32x4*)&KVi[ tk       * 64 + ((s ^ tks) << 2)];
            f32x4 ki1 = *(const f32x4*)&KVi[(tk + 32) * 64 + ((s ^ tks) << 2)];
#pragma unroll
            for (int i = 0; i < 4; ++i) {
                const int q = tq8 * 4 + i;
                f32x4 q_r = *(const f32x4*)&Qr[q][d4];
                f32x4 q_i = *(const f32x4*)&Qi[q][d4];
#pragma unroll
                for (int x = 0; x < 4; ++x) {
                    ar[i][0] += q_r[x] * kr0[x] - q_i[x] * ki0[x];
                    pr[i][0] += q_r[x] * ki0[x] + q_i[x] * kr0[x];
                    ar[i][1] += q_r[x] * kr1[x] - q_i[x] * ki1[x];
                    pr[i][1] += q_r[x] * ki1[x] + q_i[x] * kr1[x];
                }
            }
        }

        // prefetch V into regs (overlaps softmax)
        f32x4 va0 = *(const f32x4*)(vr_g + go),        va1 = *(const f32x4*)(vr_g + go + 4);
        f32x4 va2 = *(const f32x4*)(vr_g + go + 2048), va3 = *(const f32x4*)(vr_g + go + 2052);
        f32x4 vb0 = *(const f32x4*)(vi_g + go),        vb1 = *(const f32x4*)(vi_g + go + 4);
        f32x4 vb2 = *(const f32x4*)(vi_g + go + 2048), vb3 = *(const f32x4*)(vi_g + go + 2052);

        // ----- scores + online softmax (rows owned by 32-lane groups) -----
#pragma unroll
        for (int i = 0; i < 4; ++i) {
            float s2[2];
#pragma unroll
            for (int jj = 0; jj < 2; ++jj) {
                float amp = ar[i][jj] * amix;
                float ph  = pr[i][jj] * pmix;
                float sn, cs;
                __sincosf(ph, &sn, &cs);
                float sig = 1.f / (1.f + __expf(-amp * sn));
                s2[jj] = amp * cs * sig;
            }
            float rm = fmaxf(s2[0], s2[1]);
#pragma unroll
            for (int ofs = 1; ofs < 32; ofs <<= 1) rm = fmaxf(rm, __shfl_xor(rm, ofs, 32));
            const float mn = fmaxf(m_[i], rm);
            const float sc = __expf(m_[i] - mn);
            const float pa = __expf(s2[0] - mn), pb = __expf(s2[1] - mn);
            float rs = pa + pb;
#pragma unroll
            for (int ofs = 1; ofs < 32; ofs <<= 1) rs += __shfl_xor(rs, ofs, 32);
            l_[i] = l_[i] * sc + rs;
            m_[i] = mn;
            sc_[i] = sc;
            P[tq8 * 4 + i][tk]      = pa;
            P[tq8 * 4 + i][tk + 32] = pb;
        }
        __syncthreads();   // (C) S reads done, P visible
        {
            int r0 = rr, r1 = rr + 32;
            *(f32x4*)&KVr[r0 * 64 + (((s0    ) ^ sw_r) << 2)] = va0;
            *(f32x4*)&KVr[r0 * 64 + (((s0 + 1) ^ sw_r) << 2)] = va1;
            *(f32x4*)&KVr[r1 * 64 + (((s0    ) ^ sw_r) << 2)] = va2;
            *(f32x4*)&KVr[r1 * 64 + (((s0 + 1) ^ sw_r) << 2)] = va3;
            *(f32x4*)&KVi[r0 * 64 + (((s0    ) ^ sw_r) << 2)] = vb0;
            *(f32x4*)&KVi[r0 * 64 + (((s0 + 1) ^ sw_r) << 2)] = vb1;
            *(f32x4*)&KVi[r1 * 64 + (((s0    ) ^ sw_r) << 2)] = vb2;
            *(f32x4*)&KVi[r1 * 64 + (((s0 + 1) ^ sw_r) << 2)] = vb3;
        }
        __syncthreads();   // (D) V ready

        // ----- O phase: cols tk*4 of 128 (tk<16 -> real, else imag) -----
#pragma unroll
        for (int i = 0; i < 4; ++i) o_[i] *= sc_[i];
        const float* vbase = (tk < 16) ? KVr : KVi;
#pragma unroll 4
        for (int kk4 = 0; kk4 < 16; ++kk4) {
            f32x4 p4[4];
#pragma unroll
            for (int i = 0; i < 4; ++i) p4[i] = *(const f32x4*)&P[tq8 * 4 + i][kk4 * 4];
#pragma unroll
            for (int jj = 0; jj < 4; ++jj) {
                const int row = kk4 * 4 + jj;
                f32x4 vv = *(const f32x4*)(vbase + row * 64 + ((tks ^ (row & 15)) << 2));
#pragma unroll
                for (int i = 0; i < 4; ++i) o_[i] += p4[i][jj] * vv;
            }
        }
    }

    // ----- write output -----
#pragma unroll
    for (int i = 0; i < 4; ++i) {
        const int n = qt * 32 + tq8 * 4 + i;
        const float inv = 1.f / l_[i];
        f32x4 o = o_[i] * inv;
        *(f32x4*)(Out + (size_t)(bidx * NSEQ + n) * TWOC + h * 128 + tk * 4) = o;
    }
}

// ---------------------------------------------------------------------------
extern "C" void kernel_launch(void* const* d_in, const int* in_sizes, int n_in,
                              void* d_out, int out_size, void* d_ws, size_t ws_size,
                              hipStream_t stream) {
    (void)in_sizes; (void)n_in; (void)out_size; (void)ws_size;
    const float* x      = (const float*)d_in[0];
    const float* q_w    = (const float*)d_in[1];
    const float* q_b    = (const float*)d_in[2];
    const float* q_g    = (const float*)d_in[3];
    const float* q_beta = (const float*)d_in[4];
    const float* k_w    = (const float*)d_in[5];
    const float* k_b    = (const float*)d_in[6];
    const float* k_g    = (const float*)d_in[7];
    const float* k_beta = (const float*)d_in[8];
    const float* v_w    = (const float*)d_in[9];
    const float* v_b    = (const float*)d_in[10];
    const float* v_g    = (const float*)d_in[11];
    const float* v_beta = (const float*)d_in[12];
    const float* amp_mix   = (const float*)d_in[13];
    const float* phase_mix = (const float*)d_in[14];

    // d_out (16.7 MB) doubles as X-panel scratch (10.5 MB) until attn
    // overwrites it at the end.  ws: [0,31.5MB) W panels, then q/k/v f32.
    unsigned short* Xpan = (unsigned short*)d_out;
    unsigned short* Wpan = (unsigned short*)d_ws;
    float* qbuf = (float*)((char*)d_ws + 3u * WPAN_Z_BYTES);
    float* kbuf = qbuf + (size_t)4194304;
    float* vbuf = kbuf + (size_t)4194304;

    split_x<<<1024, 256, 0, stream>>>(x, Xpan);
    split_w<<<dim3(64, 16, 3), 256, 0, stream>>>(q_w, k_w, v_w, Wpan);
    mfma_gemm<<<dim3(16, 16, 3), 256, 0, stream>>>(
        Xpan, Wpan, q_b, k_b, v_b, qbuf, kbuf, vbuf);
    ln_relu<<<dim3(2048, 3), 256, 0, stream>>>(
        qbuf, kbuf, vbuf, q_g, q_beta, k_g, k_beta, v_g, v_beta);
    attn<<<dim3(32, 32), 256, 0, stream>>>(
        qbuf, kbuf, vbuf, amp_mix, phase_mix, (float*)d_out);
}

// Round 3
// 321.128 us; speedup vs baseline: 2.9466x; 2.0363x over previous
//
#include <hip/hip_runtime.h>
#include <math.h>

// Problem constants (B=2, N=1024, C=1024, H=16, D=64)
#define NSEQ   1024
#define KDIM   1024
#define TWOC   2048
#define NB     65536   // NSEQ * 64 floats per (b,h,part) plane

typedef float  f32x4  __attribute__((ext_vector_type(4)));
typedef short  short8 __attribute__((ext_vector_type(8)));
typedef short  short4v __attribute__((ext_vector_type(4)));
typedef unsigned int u32x4 __attribute__((ext_vector_type(4)));
typedef __bf16 bf16x8 __attribute__((ext_vector_type(8)));

// GEMM panel geometry (unchanged from round 2)
#define PANROW   40
#define PANHALF  10240
#define PANPAIR  20480
#define NPAN_K   32
#define WPAN_Z_BYTES 10485760u

// Attention panel geometry
#define QPLANE   131072          // 1024*128 elements per (bh,half)
#define KROWB    272             // 136 bf16 per row
#define KPLANEB  278528          // 1024*272 bytes per (bh,half)
#define VPLANE   131072          // 128*1024 elements per (bh,half)

// ws offsets (bytes)
#define QPAN_OFF   0ul
#define KPAN_OFF   16777216ul
#define VTPAN_OFF  34603008ul
#define QBUF_OFF   51380224ul
#define KBUF_OFF   68157440ul
#define VBUF_OFF   84934656ul

__device__ __forceinline__ unsigned short bf16_rne(float x) {
    unsigned int u = __float_as_uint(x);
    u += 0x7fffu + ((u >> 16) & 1u);
    return (unsigned short)(u >> 16);
}

__device__ __forceinline__ void gload_lds16(const void* g, void* l) {
    __builtin_amdgcn_global_load_lds(
        (const __attribute__((address_space(1))) unsigned int*)g,
        (__attribute__((address_space(3))) unsigned int*)l, 16, 0, 0);
}

__device__ __forceinline__ bf16x8 bneg(bf16x8 v) {
    u32x4 u = __builtin_bit_cast(u32x4, v);
    u ^= 0x80008000u;
    return __builtin_bit_cast(bf16x8, u);
}

// ---------------------------------------------------------------------------
// split_x: X[2048][1024] f32 -> hi/lo bf16 panels (GEMM A operand).
// ---------------------------------------------------------------------------
__global__ __launch_bounds__(256)
void split_x(const float* __restrict__ X, unsigned short* __restrict__ Xpan)
{
    const int c  = blockIdx.x * 256 + threadIdx.x;
    const int m  = c >> 7;
    const int k0 = (c & 127) << 3;
    f32x4 v0 = *(const f32x4*)(X + (size_t)m * KDIM + k0);
    f32x4 v1 = *(const f32x4*)(X + (size_t)m * KDIM + k0 + 4);
    float xv[8] = {v0[0],v0[1],v0[2],v0[3],v1[0],v1[1],v1[2],v1[3]};
    short8 h8, l8;
#pragma unroll
    for (int j = 0; j < 8; ++j) {
        unsigned short h = bf16_rne(xv[j]);
        float hf = __uint_as_float((unsigned int)h << 16);
        unsigned short lo = bf16_rne(xv[j] - hf);
        h8[j] = (short)h; l8[j] = (short)lo;
    }
    const int mb = m >> 7, ml = m & 127, ks = k0 >> 5, kl = k0 & 31;
    char* base = (char*)Xpan + (size_t)(mb * NPAN_K + ks) * PANPAIR + ml * 80 + kl * 2;
    *(short8*)base = h8;
    *(short8*)(base + PANHALF) = l8;
}

// ---------------------------------------------------------------------------
// split_w: W[1024][2048] f32 -> transposed hi/lo bf16 panels (GEMM B operand).
// ---------------------------------------------------------------------------
__global__ __launch_bounds__(256)
void split_w(const float* __restrict__ Wq, const float* __restrict__ Wk,
             const float* __restrict__ Wv, unsigned short* __restrict__ Wpan)
{
    const int z = blockIdx.z;
    const float* W = (z == 0) ? Wq : (z == 1) ? Wk : Wv;
    char* pan = (char*)Wpan + (size_t)z * WPAN_Z_BYTES;

    __shared__ __align__(16) float T[64][36];
    const int t  = threadIdx.x;
    const int nt = blockIdx.x;
    const int kt = blockIdx.y;
    const int kk = t >> 3, cc = (t & 7) * 4;
#pragma unroll
    for (int i = 0; i < 2; ++i) {
        int kr = kk + i * 32;
        *(f32x4*)&T[kr][cc] = *(const f32x4*)(W + (size_t)(kt * 64 + kr) * TWOC + nt * 32 + cc);
    }
    __syncthreads();
    const int n_i = t & 31, kc = t >> 5;
    const int k0 = kc * 8;
    short8 h8, l8;
#pragma unroll
    for (int x = 0; x < 8; ++x) {
        float xv = T[k0 + x][n_i];
        unsigned short h = bf16_rne(xv);
        float hf = __uint_as_float((unsigned int)h << 16);
        unsigned short lo = bf16_rne(xv - hf);
        h8[x] = (short)h; l8[x] = (short)lo;
    }
    const int n_g = nt * 32 + n_i;
    const int nbk = n_g >> 7, nl = n_g & 127;
    const int k_g = kt * 64 + k0;
    const int ks = k_g >> 5, kl = k_g & 31;
    char* base = pan + (size_t)(nbk * NPAN_K + ks) * PANPAIR + nl * 80 + kl * 2;
    *(short8*)base = h8;
    *(short8*)(base + PANHALF) = l8;
}

// ---------------------------------------------------------------------------
// mfma_gemm: Y = X @ W + bias (split-bf16), output [bh*2+part][n][d] f32.
// ---------------------------------------------------------------------------
__global__ __launch_bounds__(256)
void mfma_gemm(const unsigned short* __restrict__ Xpan,
               const unsigned short* __restrict__ Wpan,
               const float* __restrict__ Bq, const float* __restrict__ Bk,
               const float* __restrict__ Bv,
               float* __restrict__ Yq, float* __restrict__ Yk, float* __restrict__ Yv)
{
    __shared__ __align__(16) char AB[40960];
    const int t = threadIdx.x, l = t & 63, w = t >> 6;
    const int wm = w >> 1, wn = w & 1;
    const int nb = blockIdx.x, mb = blockIdx.y, z = blockIdx.z;
    const char* Apan = (const char*)Xpan + (size_t)mb * NPAN_K * PANPAIR;
    const char* Bpan = (const char*)Wpan + (size_t)z * WPAN_Z_BYTES
                                        + (size_t)nb * NPAN_K * PANPAIR;
    const float* bias = (z == 0) ? Bq : (z == 1) ? Bk : Bv;
    float* Y = (z == 0) ? Yq : (z == 1) ? Yk : Yv;

    f32x4 acc[4][4];
#pragma unroll
    for (int i = 0; i < 4; ++i)
#pragma unroll
        for (int j = 0; j < 4; ++j) acc[i][j] = (f32x4){0.f, 0.f, 0.f, 0.f};

    {
#pragma unroll
        for (int r = 0; r < 5; ++r) {
            int off = r * 4096 + t * 16;
            gload_lds16(Apan + off, AB + off);
            gload_lds16(Bpan + off, AB + 20480 + off);
        }
    }
    const int lg  = (l >> 4) * 16;
    const int l15 = l & 15;

    for (int ks = 0; ks < 32; ++ks) {
        __syncthreads();
        short8 ahi[4], alo[4];
#pragma unroll
        for (int fi = 0; fi < 4; ++fi) {
            int row = wm * 64 + fi * 16 + l15;
            ahi[fi] = *(const short8*)(AB + row * 80 + lg);
            alo[fi] = *(const short8*)(AB + PANHALF + row * 80 + lg);
        }
#pragma unroll
        for (int fj = 0; fj < 4; ++fj) {
            int rn = wn * 64 + fj * 16 + l15;
            short8 bh = *(const short8*)(AB + 20480 + rn * 80 + lg);
            short8 bl = *(const short8*)(AB + 30720 + rn * 80 + lg);
            bf16x8 bhv = __builtin_bit_cast(bf16x8, bh);
            bf16x8 blv = __builtin_bit_cast(bf16x8, bl);
#pragma unroll
            for (int fi = 0; fi < 4; ++fi) {
                bf16x8 ahv = __builtin_bit_cast(bf16x8, ahi[fi]);
                bf16x8 alv = __builtin_bit_cast(bf16x8, alo[fi]);
                acc[fi][fj] = __builtin_amdgcn_mfma_f32_16x16x32_bf16(ahv, bhv, acc[fi][fj], 0, 0, 0);
                acc[fi][fj] = __builtin_amdgcn_mfma_f32_16x16x32_bf16(ahv, blv, acc[fi][fj], 0, 0, 0);
                acc[fi][fj] = __builtin_amdgcn_mfma_f32_16x16x32_bf16(alv, bhv, acc[fi][fj], 0, 0, 0);
            }
        }
        __syncthreads();
        if (ks < 31) {
            const char* ga = Apan + (size_t)(ks + 1) * PANPAIR;
            const char* gb = Bpan + (size_t)(ks + 1) * PANPAIR;
#pragma unroll
            for (int r = 0; r < 5; ++r) {
                int off = r * 4096 + t * 16;
                gload_lds16(ga + off, AB + off);
                gload_lds16(gb + off, AB + 20480 + off);
            }
        }
    }

#pragma unroll
    for (int fj = 0; fj < 4; ++fj) {
        int ccol = nb * 128 + wn * 64 + fj * 16 + l15;
        float bb = bias[ccol];
        int hh = ccol >> 7, pp = (ccol >> 6) & 1, d0 = ccol & 63;
        float* ybase = Y + (size_t)(hh * 2 + pp) * NB + d0;
#pragma unroll
        for (int fi = 0; fi < 4; ++fi) {
            int mb4 = mb * 128 + wm * 64 + fi * 16 + (l >> 4) * 4;
#pragma unroll
            for (int r = 0; r < 4; ++r) {
                int mg = mb4 + r;
                int bidx = mg >> 10, n = mg & 1023;
                ybase[(size_t)(bidx * 32) * NB + n * 64] = acc[fi][fj][r] + bb;
            }
        }
    }
}

// ---------------------------------------------------------------------------
// ln_relu: LayerNorm+gamma/beta+ReLU. For q,k: write bf16 hi/lo panels
// (Qpan [bh*2+half][n][128], Kpan [bh*2+half][n][136 padded]). For v: f32
// in-place (consumed by vsplit). Grid (2048, 3), 256 threads.
// ---------------------------------------------------------------------------
__global__ __launch_bounds__(256)
void ln_relu(float* __restrict__ Yq, float* __restrict__ Yk, float* __restrict__ Yv,
             const float* __restrict__ Gq, const float* __restrict__ BTq,
             const float* __restrict__ Gk, const float* __restrict__ BTk,
             const float* __restrict__ Gv, const float* __restrict__ BTv,
             unsigned short* __restrict__ Qpan, unsigned short* __restrict__ Kpan)
{
    float* Y; const float* G; const float* Bt;
    if (blockIdx.y == 0)      { Y = Yq; G = Gq; Bt = BTq; }
    else if (blockIdx.y == 1) { Y = Yk; G = Gk; Bt = BTk; }
    else                      { Y = Yv; G = Gv; Bt = BTv; }

    const int r    = blockIdx.x;
    const int bidx = r >> 10;
    const int n    = r & 1023;
    const int t    = threadIdx.x;
    const int e0   = t * 8;
    const int chunk = e0 >> 6;
    const int d     = e0 & 63;

    float* p = Y + (size_t)(bidx * 32 + chunk) * NB + n * 64 + d;
    f32x4 v0 = *(f32x4*)p;
    f32x4 v1 = *(f32x4*)(p + 4);
    float xv[8] = {v0[0],v0[1],v0[2],v0[3],v1[0],v1[1],v1[2],v1[3]};

    __shared__ float red[8];
    float s = 0.f;
#pragma unroll
    for (int j = 0; j < 8; ++j) s += xv[j];
#pragma unroll
    for (int off = 32; off > 0; off >>= 1) s += __shfl_down(s, off);
    const int lane = t & 63, wid = t >> 6;
    if (lane == 0) red[wid] = s;
    __syncthreads();
    const float mean = (red[0] + red[1] + red[2] + red[3]) * (1.f / 2048.f);
    __syncthreads();

    float sq = 0.f;
#pragma unroll
    for (int j = 0; j < 8; ++j) { float dx = xv[j] - mean; sq += dx * dx; }
#pragma unroll
    for (int off = 32; off > 0; off >>= 1) sq += __shfl_down(sq, off);
    if (lane == 0) red[wid] = sq;
    __syncthreads();
    const float var  = (red[0] + red[1] + red[2] + red[3]) * (1.f / 2048.f);
    const float rstd = 1.f / sqrtf(var + 1e-5f);

    float yv[8];
#pragma unroll
    for (int j = 0; j < 8; ++j)
        yv[j] = fmaxf((xv[j] - mean) * rstd * G[e0 + j] + Bt[e0 + j], 0.f);

    if (blockIdx.y == 2) {
        f32x4 o0, o1;
#pragma unroll
        for (int j = 0; j < 4; ++j) { o0[j] = yv[j]; o1[j] = yv[j + 4]; }
        *(f32x4*)p       = o0;
        *(f32x4*)(p + 4) = o1;
        return;
    }

    // split + panel write for q/k
    short8 h8, l8;
#pragma unroll
    for (int j = 0; j < 8; ++j) {
        unsigned short hh = bf16_rne(yv[j]);
        float hf = __uint_as_float((unsigned int)hh << 16);
        unsigned short lo = bf16_rne(yv[j] - hf);
        h8[j] = (short)hh; l8[j] = (short)lo;
    }
    const int bh   = bidx * 16 + (e0 >> 7);
    const int dim0 = e0 & 127;
    if (blockIdx.y == 0) {
        unsigned short* dst = Qpan + ((size_t)(bh * 2) * 1024 + n) * 128 + dim0;
        *(short8*)dst = h8;
        *(short8*)(dst + QPLANE) = l8;
    } else {
        unsigned short* dst = Kpan + ((size_t)(bh * 2) * 1024 + n) * 136 + dim0;
        *(short8*)dst = h8;
        *(short8*)(dst + (size_t)1024 * 136) = l8;
    }
}

// ---------------------------------------------------------------------------
// vsplit: vbuf f32 [bh*2+part][n][d] -> Vtpan bf16 hi/lo [bh*2+half][d2][n]
// (transposed). Grid (32 bh, 32 ntile), 256 threads.
// ---------------------------------------------------------------------------
__global__ __launch_bounds__(256)
void vsplit(const float* __restrict__ vbuf, unsigned short* __restrict__ Vtpan)
{
    __shared__ __align__(16) float T[32][132];
    const int bh = blockIdx.x, nt = blockIdx.y;
    const int n0 = nt * 32;
    const int t = threadIdx.x;
    {
        const int nl = t >> 3, cg = t & 7;
        const int part = cg >> 2, dq = (cg & 3) * 16;
        const float* src = vbuf + (size_t)(bh * 2 + part) * NB + (n0 + nl) * 64 + dq;
#pragma unroll
        for (int i = 0; i < 4; ++i)
            *(f32x4*)&T[nl][cg * 16 + i * 4] = *(const f32x4*)(src + i * 4);
    }
    __syncthreads();
    const int d2 = t & 127, nh = t >> 7;
    unsigned short hv[16], lv[16];
#pragma unroll
    for (int j = 0; j < 16; ++j) {
        float v = T[nh * 16 + j][d2];
        unsigned short hh = bf16_rne(v);
        float hf = __uint_as_float((unsigned int)hh << 16);
        hv[j] = hh; lv[j] = bf16_rne(v - hf);
    }
    unsigned short* dst = Vtpan + ((size_t)(bh * 2) * 128 + d2) * 1024 + n0 + nh * 16;
    *(short8*)dst = *(short8*)&hv[0];
    *(short8*)(dst + 8) = *(short8*)&hv[8];
    unsigned short* dstl = dst + VPLANE;
    *(short8*)dstl = *(short8*)&lv[0];
    *(short8*)(dstl + 8) = *(short8*)&lv[8];
}

// ---------------------------------------------------------------------------
// attn_mfma: MFMA flash attention, swapped S^T = K @ Q^T.
// Grid 512 blocks (XCD-chunk swizzled), 256 threads (4 waves).
// Block = (bh, 64-q tile); KVBLK=32, 32 k-iterations.
// Wave w owns q-columns [w*16, w*16+16); lane: l15 = q-local, g = l>>4.
// ---------------------------------------------------------------------------
__global__ __launch_bounds__(256)
void attn_mfma(const unsigned short* __restrict__ Qpan,
               const unsigned short* __restrict__ Kpan,
               const unsigned short* __restrict__ Vtpan,
               const float* __restrict__ amp_mix, const float* __restrict__ phase_mix,
               float* __restrict__ Out)
{
    __shared__ __align__(16) char Klds[2 * 8704];     // [half][32 k][272B]
    __shared__ __align__(16) char Vlds[2 * 128 * 80]; // [half*128+d2][80B]
    __shared__ __align__(16) char Plds[64 * 80];      // [q][40 bf16]
    __shared__ float sc_s[64];
    __shared__ float l_s[64];

    const int bid = blockIdx.x;
    const int swz = (bid & 7) * 64 + (bid >> 3);      // XCD-chunked
    const int bh = swz >> 4, qt = swz & 15;
    const int h = bh & 15, bidx = bh >> 4;

    const int t = threadIdx.x, l = t & 63, w = t >> 6;
    const int l15 = l & 15, g = l >> 4;

    const float amix = amp_mix[h], pmix = phase_mix[h];

    // ---- persistent Q fragments: Qf[half][db], B-operand of S^T ----
    bf16x8 Qf[2][4];
    {
        const unsigned short* qb = Qpan + ((size_t)(bh * 2) * 1024 + qt * 64 + w * 16 + l15) * 128
                                 + g * 8;
#pragma unroll
        for (int hf = 0; hf < 2; ++hf)
#pragma unroll
            for (int db = 0; db < 4; ++db)
                Qf[hf][db] = __builtin_bit_cast(bf16x8,
                    *(const short8*)(qb + (size_t)hf * QPLANE + db * 32));
    }

    const char* kbase = (const char*)Kpan + (size_t)(bh * 2) * KPLANEB;
    const unsigned short* vbase = Vtpan + (size_t)(bh * 2) * 128 * 1024 + (size_t)t * 1024;

    f32x4 O[8];
#pragma unroll
    for (int i = 0; i < 8; ++i) O[i] = (f32x4){0.f, 0.f, 0.f, 0.f};
    float m_ = -1e30f, l_ = 0.f;

    short8 vreg[4];

    // ---- prologue: stage tile 0 ----
    {
#pragma unroll
        for (int i = 0; i < 4; ++i) {
            int c = t + i * 256;
            int hf = c / 544, rem = c - hf * 544;
            gload_lds16(kbase + (size_t)hf * KPLANEB + rem * 16, Klds + c * 16);
        }
        if (w == 0) {
            int c = 1024 + l;
            int hf = c / 544, rem = c - hf * 544;
            gload_lds16(kbase + (size_t)hf * KPLANEB + rem * 16, Klds + c * 16);
        }
#pragma unroll
        for (int s = 0; s < 4; ++s) vreg[s] = *(const short8*)(vbase + s * 8);
#pragma unroll
        for (int s = 0; s < 4; ++s) *(short8*)(Vlds + t * 80 + s * 16) = vreg[s];
    }

    for (int kt = 0; kt < 32; ++kt) {
        __syncthreads();   // (1) staged K/V visible

        // ----- S^T phase: amp/ph accumulators per fi (k-row block) -----
        f32x4 aA[2], pA[2];
#pragma unroll
        for (int fi = 0; fi < 2; ++fi) {
            aA[fi] = (f32x4){0.f, 0.f, 0.f, 0.f};
            pA[fi] = (f32x4){0.f, 0.f, 0.f, 0.f};
            const char* kr = Klds + (fi * 16 + l15) * 272 + g * 16;
            bf16x8 Fh[4], Fl[4];
#pragma unroll
            for (int db = 0; db < 4; ++db) {
                Fh[db] = __builtin_bit_cast(bf16x8, *(const short8*)(kr + db * 64));
                Fl[db] = __builtin_bit_cast(bf16x8, *(const short8*)(kr + 8704 + db * 64));
            }
            bf16x8 Nh[2] = { bneg(Fh[2]), bneg(Fh[3]) };
            bf16x8 Nl[2] = { bneg(Fl[2]), bneg(Fl[3]) };
#pragma unroll
            for (int db = 0; db < 4; ++db) {
                bf16x8 Ah = (db < 2) ? Fh[db] : Nh[db - 2];
                bf16x8 Al = (db < 2) ? Fl[db] : Nl[db - 2];
                aA[fi] = __builtin_amdgcn_mfma_f32_16x16x32_bf16(Ah, Qf[0][db], aA[fi], 0, 0, 0);
                aA[fi] = __builtin_amdgcn_mfma_f32_16x16x32_bf16(Ah, Qf[1][db], aA[fi], 0, 0, 0);
                aA[fi] = __builtin_amdgcn_mfma_f32_16x16x32_bf16(Al, Qf[0][db], aA[fi], 0, 0, 0);
                bf16x8 Ph = Fh[db ^ 2];
                bf16x8 Pl = Fl[db ^ 2];
                pA[fi] = __builtin_amdgcn_mfma_f32_16x16x32_bf16(Ph, Qf[0][db], pA[fi], 0, 0, 0);
                pA[fi] = __builtin_amdgcn_mfma_f32_16x16x32_bf16(Ph, Qf[1][db], pA[fi], 0, 0, 0);
                pA[fi] = __builtin_amdgcn_mfma_f32_16x16x32_bf16(Pl, Qf[0][db], pA[fi], 0, 0, 0);
            }
        }

        // ----- scores -----
        float sv[2][4];
#pragma unroll
        for (int fi = 0; fi < 2; ++fi)
#pragma unroll
            for (int r = 0; r < 4; ++r) {
                float amp = aA[fi][r] * amix;
                float ph  = pA[fi][r] * pmix;
                float sn, cs;
                __sincosf(ph, &sn, &cs);
                float sig = 1.f / (1.f + __expf(-amp * sn));
                sv[fi][r] = amp * cs * sig;
            }

        // ----- online softmax (per q-column; column = l15, partners l^16,l^32) -----
        float rm = sv[0][0];
#pragma unroll
        for (int fi = 0; fi < 2; ++fi)
#pragma unroll
            for (int r = 0; r < 4; ++r) rm = fmaxf(rm, sv[fi][r]);
        rm = fmaxf(rm, __shfl_xor(rm, 16));
        rm = fmaxf(rm, __shfl_xor(rm, 32));
        const float mn  = fmaxf(m_, rm);
        const float scl = __expf(m_ - mn);
        float pv[2][4];
        float rs = 0.f;
#pragma unroll
        for (int fi = 0; fi < 2; ++fi)
#pragma unroll
            for (int r = 0; r < 4; ++r) { pv[fi][r] = __expf(sv[fi][r] - mn); rs += pv[fi][r]; }
        rs += __shfl_xor(rs, 16);
        rs += __shfl_xor(rs, 32);
        l_ = l_ * scl + rs;
        m_ = mn;

#pragma unroll
        for (int fi = 0; fi < 2; ++fi) {
            short4v pk;
#pragma unroll
            for (int r = 0; r < 4; ++r) pk[r] = (short)bf16_rne(pv[fi][r]);
            *(short4v*)(Plds + (w * 16 + l15) * 80 + fi * 32 + g * 8) = pk;
        }
        if (g == 0) sc_s[w * 16 + l15] = scl;

        __syncthreads();   // (2) P + sc visible; K/V reads of this kt done for S

        // ----- issue next-tile staging (overlaps PV) -----
        if (kt < 31) {
            const char* ks = kbase + (size_t)(kt + 1) * 8704;
#pragma unroll
            for (int i = 0; i < 4; ++i) {
                int c = t + i * 256;
                int hf = c / 544, rem = c - hf * 544;
                gload_lds16(ks + (size_t)hf * (KPLANEB - 0) + rem * 16 - (hf ? (size_t)8704 : 0) + (hf ? (size_t)8704 : 0), Klds + c * 16);
            }
            if (w == 0) {
                int c = 1024 + l;
                int hf = c / 544, rem = c - hf * 544;
                gload_lds16(ks + (size_t)hf * KPLANEB + rem * 16, Klds + c * 16);
            }
#pragma unroll
            for (int s = 0; s < 4; ++s) vreg[s] = *(const short8*)(vbase + (kt + 1) * 32 + s * 8);
        }

        // ----- PV phase -----
        f32x4 scv;
#pragma unroll
        for (int r = 0; r < 4; ++r) scv[r] = sc_s[w * 16 + g * 4 + r];
        bf16x8 Pf = __builtin_bit_cast(bf16x8,
            *(const short8*)(Plds + (w * 16 + l15) * 80 + g * 16));
#pragma unroll
        for (int nt = 0; nt < 8; ++nt) {
            bf16x8 Vh = __builtin_bit_cast(bf16x8,
                *(const short8*)(Vlds + (nt * 16 + l15) * 80 + g * 16));
            bf16x8 Vl = __builtin_bit_cast(bf16x8,
                *(const short8*)(Vlds + (128 * 80) + (nt * 16 + l15) * 80 + g * 16));
            O[nt] *= scv;
            O[nt] = __builtin_amdgcn_mfma_f32_16x16x32_bf16(Pf, Vh, O[nt], 0, 0, 0);
            O[nt] = __builtin_amdgcn_mfma_f32_16x16x32_bf16(Pf, Vl, O[nt], 0, 0, 0);
        }

        __syncthreads();   // (3) all waves done reading Vlds/Plds

        if (kt < 31) {
#pragma unroll
            for (int s = 0; s < 4; ++s) *(short8*)(Vlds + t * 80 + s * 16) = vreg[s];
        }
    }

    // ----- epilogue -----
    if (g == 0) l_s[w * 16 + l15] = l_;
    __syncthreads();
    f32x4 invv;
#pragma unroll
    for (int r = 0; r < 4; ++r) invv[r] = 1.f / l_s[w * 16 + g * 4 + r];
#pragma unroll
    for (int nt = 0; nt < 8; ++nt) {
#pragma unroll
        for (int r = 0; r < 4; ++r) {
            const int n = qt * 64 + w * 16 + g * 4 + r;
            Out[(size_t)(bidx * NSEQ + n) * TWOC + h * 128 + nt * 16 + l15] = O[nt][r] * invv[r];
        }
    }
}

// ---------------------------------------------------------------------------
extern "C" void kernel_launch(void* const* d_in, const int* in_sizes, int n_in,
                              void* d_out, int out_size, void* d_ws, size_t ws_size,
                              hipStream_t stream) {
    (void)in_sizes; (void)n_in; (void)out_size; (void)ws_size;
    const float* x      = (const float*)d_in[0];
    const float* q_w    = (const float*)d_in[1];
    const float* q_b    = (const float*)d_in[2];
    const float* q_g    = (const float*)d_in[3];
    const float* q_beta = (const float*)d_in[4];
    const float* k_w    = (const float*)d_in[5];
    const float* k_b    = (const float*)d_in[6];
    const float* k_g    = (const float*)d_in[7];
    const float* k_beta = (const float*)d_in[8];
    const float* v_w    = (const float*)d_in[9];
    const float* v_b    = (const float*)d_in[10];
    const float* v_g    = (const float*)d_in[11];
    const float* v_beta = (const float*)d_in[12];
    const float* amp_mix   = (const float*)d_in[13];
    const float* phase_mix = (const float*)d_in[14];

    char* ws = (char*)d_ws;
    // Region A [0, 51.4 MB): attn panels; Wpan aliases its start (dead after gemm)
    unsigned short* Qpan  = (unsigned short*)(ws + QPAN_OFF);
    unsigned short* Kpan  = (unsigned short*)(ws + KPAN_OFF);
    unsigned short* Vtpan = (unsigned short*)(ws + VTPAN_OFF);
    unsigned short* Wpan  = (unsigned short*)(ws + QPAN_OFF);
    // Region B [51.4, 99.7 MB): f32 GEMM outputs
    float* qbuf = (float*)(ws + QBUF_OFF);
    float* kbuf = (float*)(ws + KBUF_OFF);
    float* vbuf = (float*)(ws + VBUF_OFF);
    // d_out doubles as X-panel scratch until attn overwrites it
    unsigned short* Xpan = (unsigned short*)d_out;

    split_x<<<1024, 256, 0, stream>>>(x, Xpan);
    split_w<<<dim3(64, 16, 3), 256, 0, stream>>>(q_w, k_w, v_w, Wpan);
    mfma_gemm<<<dim3(16, 16, 3), 256, 0, stream>>>(
        Xpan, Wpan, q_b, k_b, v_b, qbuf, kbuf, vbuf);
    ln_relu<<<dim3(2048, 3), 256, 0, stream>>>(
        qbuf, kbuf, vbuf, q_g, q_beta, k_g, k_beta, v_g, v_beta, Qpan, Kpan);
    vsplit<<<dim3(32, 32), 256, 0, stream>>>(vbuf, Vtpan);
    attn_mfma<<<512, 256, 0, stream>>>(
        Qpan, Kpan, Vtpan, amp_mix, phase_mix, (float*)d_out);
}

// Round 4
// 299.761 us; speedup vs baseline: 3.1567x; 1.0713x over previous
//
#include <hip/hip_runtime.h>
#include <math.h>

// Problem constants (B=2, N=1024, C=1024, H=16, D=64)
#define NSEQ   1024
#define KDIM   1024
#define TWOC   2048
#define NB     65536   // NSEQ * 64 floats per (b,h,part) plane

typedef float  f32x4  __attribute__((ext_vector_type(4)));
typedef short  short8 __attribute__((ext_vector_type(8)));
typedef short  short4v __attribute__((ext_vector_type(4)));
typedef unsigned int u32x4 __attribute__((ext_vector_type(4)));
typedef __bf16 bf16x8 __attribute__((ext_vector_type(8)));
typedef _Float16 half8 __attribute__((ext_vector_type(8)));

// GEMM panel geometry
#define PANROW   40
#define PANHALF  10240
#define PANPAIR  20480
#define NPAN_K   32
#define WPAN_Z_BYTES 10485760u

// Attention panel geometry
#define QPLANE   131072          // 1024*128 elements per (bh,half)
#define KPLANEB  278528          // 1024*272 bytes per (bh,half)
#define VPLANEB  262144          // 128*1024*2 bytes per bh (fp16, single)

// ws offsets (bytes)
#define QPAN_OFF   0ul
#define KPAN_OFF   16777216ul
#define VTPAN_OFF  34603008ul
#define QBUF_OFF   51380224ul
#define KBUF_OFF   68157440ul
#define VBUF_OFF   84934656ul

__device__ __forceinline__ unsigned short bf16_rne(float x) {
    unsigned int u = __float_as_uint(x);
    u += 0x7fffu + ((u >> 16) & 1u);
    return (unsigned short)(u >> 16);
}

__device__ __forceinline__ void gload_lds16(const void* g, void* l) {
    __builtin_amdgcn_global_load_lds(
        (const __attribute__((address_space(1))) unsigned int*)g,
        (__attribute__((address_space(3))) unsigned int*)l, 16, 0, 0);
}

__device__ __forceinline__ bf16x8 bneg(bf16x8 v) {
    u32x4 u = __builtin_bit_cast(u32x4, v);
    u ^= 0x80008000u;
    return __builtin_bit_cast(bf16x8, u);
}

// ---------------------------------------------------------------------------
// split_x: X[2048][1024] f32 -> hi/lo bf16 panels, flat-chunk coalesced
// writes (pad slot written as zeros). Grid 1280 x 256 (one chunk/thread).
// ---------------------------------------------------------------------------
__global__ __launch_bounds__(256)
void split_x(const float* __restrict__ X, unsigned short* __restrict__ Xpan)
{
    const int c   = blockIdx.x * 256 + threadIdx.x;   // 327680 paired chunks
    const int reg = c / 640;                          // mb*32 + ks
    const int cc  = c - reg * 640;
    const int row = cc / 5, slot = cc - row * 5;
    char* base = (char*)Xpan + (size_t)reg * PANPAIR + row * 80 + slot * 16;
    if (slot == 4) {
        short8 z = (short8){0,0,0,0,0,0,0,0};
        *(short8*)base = z;
        *(short8*)(base + PANHALF) = z;
        return;
    }
    const int mb = reg >> 5, ks = reg & 31;
    const int m = mb * 128 + row, k0 = ks * 32 + slot * 8;
    f32x4 v0 = *(const f32x4*)(X + (size_t)m * KDIM + k0);
    f32x4 v1 = *(const f32x4*)(X + (size_t)m * KDIM + k0 + 4);
    float xv[8] = {v0[0],v0[1],v0[2],v0[3],v1[0],v1[1],v1[2],v1[3]};
    short8 h8, l8;
#pragma unroll
    for (int j = 0; j < 8; ++j) {
        unsigned short h = bf16_rne(xv[j]);
        float hf = __uint_as_float((unsigned int)h << 16);
        unsigned short lo = bf16_rne(xv[j] - hf);
        h8[j] = (short)h; l8[j] = (short)lo;
    }
    *(short8*)base = h8;
    *(short8*)(base + PANHALF) = l8;
}

// ---------------------------------------------------------------------------
// split_w: W[1024][2048] f32 -> transposed hi/lo bf16 panels, LDS transpose
// then flat-chunk coalesced writes. Grid (64, 16, 3).
// ---------------------------------------------------------------------------
__global__ __launch_bounds__(256)
void split_w(const float* __restrict__ Wq, const float* __restrict__ Wk,
             const float* __restrict__ Wv, unsigned short* __restrict__ Wpan)
{
    const int z = blockIdx.z;
    const float* W = (z == 0) ? Wq : (z == 1) ? Wk : Wv;
    char* pan = (char*)Wpan + (size_t)z * WPAN_Z_BYTES;

    __shared__ __align__(16) float T[64][36];
    const int t  = threadIdx.x;
    const int nt = blockIdx.x;   // n tiles of 32
    const int kt = blockIdx.y;   // k tiles of 64
    const int kk = t >> 3, cg = (t & 7) * 4;
#pragma unroll
    for (int i = 0; i < 2; ++i) {
        int kr = kk + i * 32;
        *(f32x4*)&T[kr][cg] = *(const f32x4*)(W + (size_t)(kt * 64 + kr) * TWOC + nt * 32 + cg);
    }
    __syncthreads();

    const int nbk = nt >> 2, nlb = (nt & 3) * 32;
#pragma unroll
    for (int i = 0; i < 2; ++i) {
        int c = t + i * 256;
        if (c < 320) {
            int ksi = (c >= 160) ? 1 : 0;
            int cc  = c - ksi * 160;
            int row = cc / 5, slot = cc - row * 5;
            char* base = pan + (size_t)(nbk * NPAN_K + kt * 2 + ksi) * PANPAIR
                       + (nlb + row) * 80 + slot * 16;
            short8 h8, l8;
            if (slot == 4) {
                h8 = (short8){0,0,0,0,0,0,0,0};
                l8 = h8;
            } else {
#pragma unroll
                for (int j = 0; j < 8; ++j) {
                    float xv = T[ksi * 32 + slot * 8 + j][row];
                    unsigned short h = bf16_rne(xv);
                    float hf = __uint_as_float((unsigned int)h << 16);
                    unsigned short lo = bf16_rne(xv - hf);
                    h8[j] = (short)h; l8[j] = (short)lo;
                }
            }
            *(short8*)base = h8;
            *(short8*)(base + PANHALF) = l8;
        }
    }
}

// ---------------------------------------------------------------------------
// mfma_gemm: Y = X @ W + bias (split-bf16), output [bh*2+part][n][d] f32.
// Unchanged from round 3 (passed).
// ---------------------------------------------------------------------------
__global__ __launch_bounds__(256)
void mfma_gemm(const unsigned short* __restrict__ Xpan,
               const unsigned short* __restrict__ Wpan,
               const float* __restrict__ Bq, const float* __restrict__ Bk,
               const float* __restrict__ Bv,
               float* __restrict__ Yq, float* __restrict__ Yk, float* __restrict__ Yv)
{
    __shared__ __align__(16) char AB[40960];
    const int t = threadIdx.x, l = t & 63, w = t >> 6;
    const int wm = w >> 1, wn = w & 1;
    const int nb = blockIdx.x, mb = blockIdx.y, z = blockIdx.z;
    const char* Apan = (const char*)Xpan + (size_t)mb * NPAN_K * PANPAIR;
    const char* Bpan = (const char*)Wpan + (size_t)z * WPAN_Z_BYTES
                                        + (size_t)nb * NPAN_K * PANPAIR;
    const float* bias = (z == 0) ? Bq : (z == 1) ? Bk : Bv;
    float* Y = (z == 0) ? Yq : (z == 1) ? Yk : Yv;

    f32x4 acc[4][4];
#pragma unroll
    for (int i = 0; i < 4; ++i)
#pragma unroll
        for (int j = 0; j < 4; ++j) acc[i][j] = (f32x4){0.f, 0.f, 0.f, 0.f};

    {
#pragma unroll
        for (int r = 0; r < 5; ++r) {
            int off = r * 4096 + t * 16;
            gload_lds16(Apan + off, AB + off);
            gload_lds16(Bpan + off, AB + 20480 + off);
        }
    }
    const int lg  = (l >> 4) * 16;
    const int l15 = l & 15;

    for (int ks = 0; ks < 32; ++ks) {
        __syncthreads();
        short8 ahi[4], alo[4];
#pragma unroll
        for (int fi = 0; fi < 4; ++fi) {
            int row = wm * 64 + fi * 16 + l15;
            ahi[fi] = *(const short8*)(AB + row * 80 + lg);
            alo[fi] = *(const short8*)(AB + PANHALF + row * 80 + lg);
        }
#pragma unroll
        for (int fj = 0; fj < 4; ++fj) {
            int rn = wn * 64 + fj * 16 + l15;
            short8 bh = *(const short8*)(AB + 20480 + rn * 80 + lg);
            short8 bl = *(const short8*)(AB + 30720 + rn * 80 + lg);
            bf16x8 bhv = __builtin_bit_cast(bf16x8, bh);
            bf16x8 blv = __builtin_bit_cast(bf16x8, bl);
#pragma unroll
            for (int fi = 0; fi < 4; ++fi) {
                bf16x8 ahv = __builtin_bit_cast(bf16x8, ahi[fi]);
                bf16x8 alv = __builtin_bit_cast(bf16x8, alo[fi]);
                acc[fi][fj] = __builtin_amdgcn_mfma_f32_16x16x32_bf16(ahv, bhv, acc[fi][fj], 0, 0, 0);
                acc[fi][fj] = __builtin_amdgcn_mfma_f32_16x16x32_bf16(ahv, blv, acc[fi][fj], 0, 0, 0);
                acc[fi][fj] = __builtin_amdgcn_mfma_f32_16x16x32_bf16(alv, bhv, acc[fi][fj], 0, 0, 0);
            }
        }
        __syncthreads();
        if (ks < 31) {
            const char* ga = Apan + (size_t)(ks + 1) * PANPAIR;
            const char* gb = Bpan + (size_t)(ks + 1) * PANPAIR;
#pragma unroll
            for (int r = 0; r < 5; ++r) {
                int off = r * 4096 + t * 16;
                gload_lds16(ga + off, AB + off);
                gload_lds16(gb + off, AB + 20480 + off);
            }
        }
    }

#pragma unroll
    for (int fj = 0; fj < 4; ++fj) {
        int ccol = nb * 128 + wn * 64 + fj * 16 + l15;
        float bb = bias[ccol];
        int hh = ccol >> 7, pp = (ccol >> 6) & 1, d0 = ccol & 63;
        float* ybase = Y + (size_t)(hh * 2 + pp) * NB + d0;
#pragma unroll
        for (int fi = 0; fi < 4; ++fi) {
            int mb4 = mb * 128 + wm * 64 + fi * 16 + (l >> 4) * 4;
#pragma unroll
            for (int r = 0; r < 4; ++r) {
                int mg = mb4 + r;
                int bidx = mg >> 10, n = mg & 1023;
                ybase[(size_t)(bidx * 32) * NB + n * 64] = acc[fi][fj][r] + bb;
            }
        }
    }
}

// ---------------------------------------------------------------------------
// ln_relu: LayerNorm+gamma/beta+ReLU; q,k -> bf16 hi/lo panels; v -> f32.
// Unchanged from round 3 (passed).
// ---------------------------------------------------------------------------
__global__ __launch_bounds__(256)
void ln_relu(float* __restrict__ Yq, float* __restrict__ Yk, float* __restrict__ Yv,
             const float* __restrict__ Gq, const float* __restrict__ BTq,
             const float* __restrict__ Gk, const float* __restrict__ BTk,
             const float* __restrict__ Gv, const float* __restrict__ BTv,
             unsigned short* __restrict__ Qpan, unsigned short* __restrict__ Kpan)
{
    float* Y; const float* G; const float* Bt;
    if (blockIdx.y == 0)      { Y = Yq; G = Gq; Bt = BTq; }
    else if (blockIdx.y == 1) { Y = Yk; G = Gk; Bt = BTk; }
    else                      { Y = Yv; G = Gv; Bt = BTv; }

    const int r    = blockIdx.x;
    const int bidx = r >> 10;
    const int n    = r & 1023;
    const int t    = threadIdx.x;
    const int e0   = t * 8;
    const int chunk = e0 >> 6;
    const int d     = e0 & 63;

    float* p = Y + (size_t)(bidx * 32 + chunk) * NB + n * 64 + d;
    f32x4 v0 = *(f32x4*)p;
    f32x4 v1 = *(f32x4*)(p + 4);
    float xv[8] = {v0[0],v0[1],v0[2],v0[3],v1[0],v1[1],v1[2],v1[3]};

    __shared__ float red[8];
    float s = 0.f;
#pragma unroll
    for (int j = 0; j < 8; ++j) s += xv[j];
#pragma unroll
    for (int off = 32; off > 0; off >>= 1) s += __shfl_down(s, off);
    const int lane = t & 63, wid = t >> 6;
    if (lane == 0) red[wid] = s;
    __syncthreads();
    const float mean = (red[0] + red[1] + red[2] + red[3]) * (1.f / 2048.f);
    __syncthreads();

    float sq = 0.f;
#pragma unroll
    for (int j = 0; j < 8; ++j) { float dx = xv[j] - mean; sq += dx * dx; }
#pragma unroll
    for (int off = 32; off > 0; off >>= 1) sq += __shfl_down(sq, off);
    if (lane == 0) red[wid] = sq;
    __syncthreads();
    const float var  = (red[0] + red[1] + red[2] + red[3]) * (1.f / 2048.f);
    const float rstd = 1.f / sqrtf(var + 1e-5f);

    float yv[8];
#pragma unroll
    for (int j = 0; j < 8; ++j)
        yv[j] = fmaxf((xv[j] - mean) * rstd * G[e0 + j] + Bt[e0 + j], 0.f);

    if (blockIdx.y == 2) {
        f32x4 o0, o1;
#pragma unroll
        for (int j = 0; j < 4; ++j) { o0[j] = yv[j]; o1[j] = yv[j + 4]; }
        *(f32x4*)p       = o0;
        *(f32x4*)(p + 4) = o1;
        return;
    }

    short8 h8, l8;
#pragma unroll
    for (int j = 0; j < 8; ++j) {
        unsigned short hh = bf16_rne(yv[j]);
        float hf = __uint_as_float((unsigned int)hh << 16);
        unsigned short lo = bf16_rne(yv[j] - hf);
        h8[j] = (short)hh; l8[j] = (short)lo;
    }
    const int bh   = bidx * 16 + (e0 >> 7);
    const int dim0 = e0 & 127;
    if (blockIdx.y == 0) {
        unsigned short* dst = Qpan + ((size_t)(bh * 2) * 1024 + n) * 128 + dim0;
        *(short8*)dst = h8;
        *(short8*)(dst + QPLANE) = l8;
    } else {
        unsigned short* dst = Kpan + ((size_t)(bh * 2) * 1024 + n) * 136 + dim0;
        *(short8*)dst = h8;
        *(short8*)(dst + (size_t)1024 * 136) = l8;
    }
}

// ---------------------------------------------------------------------------
// vsplit: vbuf f32 [bh*2+part][n][64] -> Vt fp16 [bh][d2(128)][n(1024)].
// LDS transpose, coalesced reads AND writes. Grid (32 bh, 16 ntile), 256 thr.
// ---------------------------------------------------------------------------
__global__ __launch_bounds__(256)
void vsplit(const float* __restrict__ vbuf, unsigned short* __restrict__ Vt)
{
    __shared__ __align__(16) unsigned short Tb[128][72];   // pitch 144 B
    const int bh = blockIdx.x, nt = blockIdx.y;
    const int n0 = nt * 64;
    const int t = threadIdx.x;
    {
        const int p = t >> 7, u = t & 127, l4 = u & 3, nl0 = u >> 2;
        const float* src0 = vbuf + (size_t)(bh * 2 + p) * NB + (size_t)n0 * 64 + l4 * 16;
#pragma unroll
        for (int rep = 0; rep < 2; ++rep) {
            const int row = nl0 + rep * 32;
            const float* sp = src0 + (size_t)row * 64;
            f32x4 a = *(const f32x4*)sp,       b = *(const f32x4*)(sp + 4);
            f32x4 c = *(const f32x4*)(sp + 8), d = *(const f32x4*)(sp + 12);
            float vv[16] = {a[0],a[1],a[2],a[3],b[0],b[1],b[2],b[3],
                            c[0],c[1],c[2],c[3],d[0],d[1],d[2],d[3]};
#pragma unroll
            for (int j = 0; j < 16; ++j)
                Tb[p * 64 + l4 * 16 + j][row] =
                    __builtin_bit_cast(unsigned short, (_Float16)vv[j]);
        }
    }
    __syncthreads();
    const int d2 = t >> 1, sseg = t & 1;
    unsigned short* dst = Vt + ((size_t)bh * 128 + d2) * 1024 + n0 + sseg * 32;
#pragma unroll
    for (int i = 0; i < 4; ++i)
        *(short8*)(dst + i * 8) = *(const short8*)&Tb[d2][sseg * 32 + i * 8];
}

// ---------------------------------------------------------------------------
// attn staging helpers (flat-chunk global_load_lds; lane-linear LDS dest).
// ---------------------------------------------------------------------------
__device__ __forceinline__ void stage_K(const char* kplane, int kt, char* dst, int t) {
#pragma unroll
    for (int i = 0; i < 4; ++i) {
        int c = t + i * 256;
        int hf = (c >= 544) ? 1 : 0;
        int rem = c - hf * 544;
        gload_lds16(kplane + (size_t)hf * KPLANEB + (size_t)kt * 8704 + rem * 16,
                    dst + c * 16);
    }
    if (t < 64) {
        int c = 1024 + t;
        gload_lds16(kplane + KPLANEB + (size_t)kt * 8704 + (c - 544) * 16,
                    dst + c * 16);
    }
}

__device__ __forceinline__ void stage_V(const char* vplane, int kt, char* dst, int t) {
#pragma unroll
    for (int i = 0; i < 2; ++i) {
        int c = t + i * 256;
        int r = c / 5, s = c - r * 5; if (s == 4) s = 3;
        gload_lds16(vplane + (size_t)r * 2048 + kt * 64 + s * 16, dst + c * 16);
    }
    if (t < 128) {
        int c = 512 + t;
        int r = c / 5, s = c - r * 5; if (s == 4) s = 3;
        gload_lds16(vplane + (size_t)r * 2048 + kt * 64 + s * 16, dst + c * 16);
    }
}

// ---------------------------------------------------------------------------
// attn_mfma: MFMA flash attention, swapped S^T = K @ Q^T.
// Double-buffered K/V staged direct-to-LDS; 2 barriers/kt (1 full, 1 lgkm-only).
// PV in fp16 (P and V). Grid 512 (XCD-swizzled), 256 threads.
// ---------------------------------------------------------------------------
__global__ __launch_bounds__(256)
void attn_mfma(const unsigned short* __restrict__ Qpan,
               const unsigned short* __restrict__ Kpan,
               const unsigned short* __restrict__ Vtpan,
               const float* __restrict__ amp_mix, const float* __restrict__ phase_mix,
               float* __restrict__ Out)
{
    __shared__ __align__(16) char Klds[2][17408];   // [hi 8704][lo 8704]
    __shared__ __align__(16) char Vlds[2][10240];   // 128 rows x 80 B (64 data+16 pad)
    __shared__ __align__(16) char Plds[5120];       // 64 q rows x 80 B (fp16)
    __shared__ float sc_s[64];
    __shared__ float l_s[64];

    const int bid = blockIdx.x;
    const int swz = (bid & 7) * 64 + (bid >> 3);      // XCD-chunked
    const int bh = swz >> 4, qt = swz & 15;
    const int h = bh & 15, bidx = bh >> 4;

    const int t = threadIdx.x, l = t & 63, w = t >> 6;
    const int l15 = l & 15, g = l >> 4;

    const float amix = amp_mix[h], pmix = phase_mix[h];

    // persistent Q fragments (B-operand of S^T)
    bf16x8 Qf[2][4];
    {
        const unsigned short* qb = Qpan
            + ((size_t)(bh * 2) * 1024 + qt * 64 + w * 16 + l15) * 128 + g * 8;
#pragma unroll
        for (int hf = 0; hf < 2; ++hf)
#pragma unroll
            for (int db = 0; db < 4; ++db)
                Qf[hf][db] = __builtin_bit_cast(bf16x8,
                    *(const short8*)(qb + (size_t)hf * QPLANE + db * 32));
    }

    const char* kbase = (const char*)Kpan + (size_t)(bh * 2) * KPLANEB;
    const char* vbase = (const char*)Vtpan + (size_t)bh * VPLANEB;

    f32x4 O[8];
#pragma unroll
    for (int i = 0; i < 8; ++i) O[i] = (f32x4){0.f, 0.f, 0.f, 0.f};
    float m_ = -1e30f, l_ = 0.f;

    // prologue: stage tile 0 into buffer 0
    stage_K(kbase, 0, Klds[0], t);
    stage_V(vbase, 0, Vlds[0], t);

    for (int kt = 0; kt < 32; ++kt) {
        __syncthreads();                 // drains vmcnt -> buf[kt&1] ready
        const int buf = kt & 1;
        if (kt < 31) {                   // prefetch kt+1 (hidden across full iter)
            stage_K(kbase, kt + 1, Klds[buf ^ 1], t);
            stage_V(vbase, kt + 1, Vlds[buf ^ 1], t);
        }
        const char* Kb = Klds[buf];

        // ----- S^T phase -----
        f32x4 aA[2], pA[2];
        __builtin_amdgcn_s_setprio(1);
#pragma unroll
        for (int fi = 0; fi < 2; ++fi) {
            aA[fi] = (f32x4){0.f, 0.f, 0.f, 0.f};
            pA[fi] = (f32x4){0.f, 0.f, 0.f, 0.f};
            const char* kr = Kb + (fi * 16 + l15) * 272 + g * 16;
            bf16x8 Fh[4], Fl[4];
#pragma unroll
            for (int db = 0; db < 4; ++db) {
                Fh[db] = __builtin_bit_cast(bf16x8, *(const short8*)(kr + db * 64));
                Fl[db] = __builtin_bit_cast(bf16x8, *(const short8*)(kr + 8704 + db * 64));
            }
            bf16x8 Nh[2] = { bneg(Fh[2]), bneg(Fh[3]) };
            bf16x8 Nl[2] = { bneg(Fl[2]), bneg(Fl[3]) };
#pragma unroll
            for (int db = 0; db < 4; ++db) {
                bf16x8 Ah = (db < 2) ? Fh[db] : Nh[db - 2];
                bf16x8 Al = (db < 2) ? Fl[db] : Nl[db - 2];
                aA[fi] = __builtin_amdgcn_mfma_f32_16x16x32_bf16(Ah, Qf[0][db], aA[fi], 0, 0, 0);
                aA[fi] = __builtin_amdgcn_mfma_f32_16x16x32_bf16(Ah, Qf[1][db], aA[fi], 0, 0, 0);
                aA[fi] = __builtin_amdgcn_mfma_f32_16x16x32_bf16(Al, Qf[0][db], aA[fi], 0, 0, 0);
                bf16x8 Ph = Fh[db ^ 2];
                bf16x8 Pl = Fl[db ^ 2];
                pA[fi] = __builtin_amdgcn_mfma_f32_16x16x32_bf16(Ph, Qf[0][db], pA[fi], 0, 0, 0);
                pA[fi] = __builtin_amdgcn_mfma_f32_16x16x32_bf16(Ph, Qf[1][db], pA[fi], 0, 0, 0);
                pA[fi] = __builtin_amdgcn_mfma_f32_16x16x32_bf16(Pl, Qf[0][db], pA[fi], 0, 0, 0);
            }
        }
        __builtin_amdgcn_s_setprio(0);

        // ----- scores -----
        float sv[2][4];
#pragma unroll
        for (int fi = 0; fi < 2; ++fi)
#pragma unroll
            for (int r = 0; r < 4; ++r) {
                float amp = aA[fi][r] * amix;
                float ph  = pA[fi][r] * pmix;
                float sn, cs;
                __sincosf(ph, &sn, &cs);
                float sig = __builtin_amdgcn_rcpf(1.f + __expf(-amp * sn));
                sv[fi][r] = amp * cs * sig;
            }

        // ----- online softmax (per q-column; partners l^16, l^32) -----
        float rm = sv[0][0];
#pragma unroll
        for (int fi = 0; fi < 2; ++fi)
#pragma unroll
            for (int r = 0; r < 4; ++r) rm = fmaxf(rm, sv[fi][r]);
        rm = fmaxf(rm, __shfl_xor(rm, 16));
        rm = fmaxf(rm, __shfl_xor(rm, 32));
        const float mn  = fmaxf(m_, rm);
        const float scl = __expf(m_ - mn);
        float pv[2][4];
        float rs = 0.f;
#pragma unroll
        for (int fi = 0; fi < 2; ++fi)
#pragma unroll
            for (int r = 0; r < 4; ++r) { pv[fi][r] = __expf(sv[fi][r] - mn); rs += pv[fi][r]; }
        rs += __shfl_xor(rs, 16);
        rs += __shfl_xor(rs, 32);
        l_ = l_ * scl + rs;
        m_ = mn;

#pragma unroll
        for (int fi = 0; fi < 2; ++fi) {
            short4v pk;
#pragma unroll
            for (int r = 0; r < 4; ++r)
                pk[r] = (short)__builtin_bit_cast(unsigned short, (_Float16)pv[fi][r]);
            *(short4v*)(Plds + (w * 16 + l15) * 80 + fi * 32 + g * 8) = pk;
        }
        if (g == 0) sc_s[w * 16 + l15] = scl;

        // lgkm-only barrier: P visible, vmcnt (staging) stays in flight
        asm volatile("s_waitcnt lgkmcnt(0)" ::: "memory");
        __builtin_amdgcn_s_barrier();
        __builtin_amdgcn_sched_barrier(0);

        // ----- PV phase (fp16) -----
        f32x4 scv;
#pragma unroll
        for (int r = 0; r < 4; ++r) scv[r] = sc_s[w * 16 + g * 4 + r];
        half8 Pf = __builtin_bit_cast(half8,
            *(const short8*)(Plds + (w * 16 + l15) * 80 + g * 16));
        const char* Vb = Vlds[buf];
        __builtin_amdgcn_s_setprio(1);
#pragma unroll
        for (int nt = 0; nt < 8; ++nt) {
            half8 Vh = __builtin_bit_cast(half8,
                *(const short8*)(Vb + (nt * 16 + l15) * 80 + g * 16));
            O[nt] *= scv;
            O[nt] = __builtin_amdgcn_mfma_f32_16x16x32_f16(Pf, Vh, O[nt], 0, 0, 0);
        }
        __builtin_amdgcn_s_setprio(0);
    }

    // ----- epilogue -----
    if (g == 0) l_s[w * 16 + l15] = l_;
    __syncthreads();
    f32x4 invv;
#pragma unroll
    for (int r = 0; r < 4; ++r) invv[r] = __builtin_amdgcn_rcpf(l_s[w * 16 + g * 4 + r]);
#pragma unroll
    for (int nt = 0; nt < 8; ++nt) {
#pragma unroll
        for (int r = 0; r < 4; ++r) {
            const int n = qt * 64 + w * 16 + g * 4 + r;
            Out[(size_t)(bidx * NSEQ + n) * TWOC + h * 128 + nt * 16 + l15] = O[nt][r] * invv[r];
        }
    }
}

// ---------------------------------------------------------------------------
extern "C" void kernel_launch(void* const* d_in, const int* in_sizes, int n_in,
                              void* d_out, int out_size, void* d_ws, size_t ws_size,
                              hipStream_t stream) {
    (void)in_sizes; (void)n_in; (void)out_size; (void)ws_size;
    const float* x      = (const float*)d_in[0];
    const float* q_w    = (const float*)d_in[1];
    const float* q_b    = (const float*)d_in[2];
    const float* q_g    = (const float*)d_in[3];
    const float* q_beta = (const float*)d_in[4];
    const float* k_w    = (const float*)d_in[5];
    const float* k_b    = (const float*)d_in[6];
    const float* k_g    = (const float*)d_in[7];
    const float* k_beta = (const float*)d_in[8];
    const float* v_w    = (const float*)d_in[9];
    const float* v_b    = (const float*)d_in[10];
    const float* v_g    = (const float*)d_in[11];
    const float* v_beta = (const float*)d_in[12];
    const float* amp_mix   = (const float*)d_in[13];
    const float* phase_mix = (const float*)d_in[14];

    char* ws = (char*)d_ws;
    unsigned short* Qpan  = (unsigned short*)(ws + QPAN_OFF);
    unsigned short* Kpan  = (unsigned short*)(ws + KPAN_OFF);
    unsigned short* Vtpan = (unsigned short*)(ws + VTPAN_OFF);
    unsigned short* Wpan  = (unsigned short*)(ws + QPAN_OFF);   // dead after gemm
    float* qbuf = (float*)(ws + QBUF_OFF);
    float* kbuf = (float*)(ws + KBUF_OFF);
    float* vbuf = (float*)(ws + VBUF_OFF);
    unsigned short* Xpan = (unsigned short*)d_out;   // scratch until attn writes

    split_x<<<1280, 256, 0, stream>>>(x, Xpan);
    split_w<<<dim3(64, 16, 3), 256, 0, stream>>>(q_w, k_w, v_w, Wpan);
    mfma_gemm<<<dim3(16, 16, 3), 256, 0, stream>>>(
        Xpan, Wpan, q_b, k_b, v_b, qbuf, kbuf, vbuf);
    ln_relu<<<dim3(2048, 3), 256, 0, stream>>>(
        qbuf, kbuf, vbuf, q_g, q_beta, k_g, k_beta, v_g, v_beta, Qpan, Kpan);
    vsplit<<<dim3(32, 16), 256, 0, stream>>>(vbuf, Vtpan);
    attn_mfma<<<512, 256, 0, stream>>>(
        Qpan, Kpan, Vtpan, amp_mix, phase_mix, (float*)d_out);
}

// Round 5
// 287.800 us; speedup vs baseline: 3.2879x; 1.0416x over previous
//
#include <hip/hip_runtime.h>
#include <math.h>

// Problem constants (B=2, N=1024, C=1024, H=16, D=64)
#define NSEQ   1024
#define KDIM   1024
#define TWOC   2048
#define NB     65536   // NSEQ * 64 floats per (b,h,part) plane

typedef float  f32x4  __attribute__((ext_vector_type(4)));
typedef short  short8 __attribute__((ext_vector_type(8)));
typedef short  short4v __attribute__((ext_vector_type(4)));
typedef unsigned int u32x4 __attribute__((ext_vector_type(4)));
typedef __bf16 bf16x8 __attribute__((ext_vector_type(8)));
typedef _Float16 half8 __attribute__((ext_vector_type(8)));

// GEMM panel geometry
#define PANROW   40
#define PANHALF  10240
#define PANPAIR  20480
#define NPAN_K   32
#define WPAN_Z_BYTES 10485760u

// Attention panel geometry
#define QPLANE   131072          // 1024*128 elements per (bh,half)
#define KPLANEB  278528          // 1024*272 bytes per (bh,half)
#define VPLANEB  262144          // 128*1024*2 bytes per bh (fp16, single)

// ws offsets (bytes)
#define QPAN_OFF   0ul
#define KPAN_OFF   16777216ul
#define VTPAN_OFF  34603008ul
#define QBUF_OFF   51380224ul
#define KBUF_OFF   68157440ul
#define VBUF_OFF   84934656ul

__device__ __forceinline__ unsigned short bf16_rne(float x) {
    unsigned int u = __float_as_uint(x);
    u += 0x7fffu + ((u >> 16) & 1u);
    return (unsigned short)(u >> 16);
}

__device__ __forceinline__ void gload_lds16(const void* g, void* l) {
    __builtin_amdgcn_global_load_lds(
        (const __attribute__((address_space(1))) unsigned int*)g,
        (__attribute__((address_space(3))) unsigned int*)l, 16, 0, 0);
}

__device__ __forceinline__ bf16x8 bneg(bf16x8 v) {
    u32x4 u = __builtin_bit_cast(u32x4, v);
    u ^= 0x80008000u;
    return __builtin_bit_cast(bf16x8, u);
}

// ---------------------------------------------------------------------------
// split_x: X[2048][1024] f32 -> hi/lo bf16 panels, flat-chunk coalesced
// writes (pad slot written as zeros). Grid 1280 x 256 (one chunk/thread).
// ---------------------------------------------------------------------------
__global__ __launch_bounds__(256)
void split_x(const float* __restrict__ X, unsigned short* __restrict__ Xpan)
{
    const int c   = blockIdx.x * 256 + threadIdx.x;   // 327680 paired chunks
    const int reg = c / 640;                          // mb*32 + ks
    const int cc  = c - reg * 640;
    const int row = cc / 5, slot = cc - row * 5;
    char* base = (char*)Xpan + (size_t)reg * PANPAIR + row * 80 + slot * 16;
    if (slot == 4) {
        short8 z = (short8){0,0,0,0,0,0,0,0};
        *(short8*)base = z;
        *(short8*)(base + PANHALF) = z;
        return;
    }
    const int mb = reg >> 5, ks = reg & 31;
    const int m = mb * 128 + row, k0 = ks * 32 + slot * 8;
    f32x4 v0 = *(const f32x4*)(X + (size_t)m * KDIM + k0);
    f32x4 v1 = *(const f32x4*)(X + (size_t)m * KDIM + k0 + 4);
    float xv[8] = {v0[0],v0[1],v0[2],v0[3],v1[0],v1[1],v1[2],v1[3]};
    short8 h8, l8;
#pragma unroll
    for (int j = 0; j < 8; ++j) {
        unsigned short h = bf16_rne(xv[j]);
        float hf = __uint_as_float((unsigned int)h << 16);
        unsigned short lo = bf16_rne(xv[j] - hf);
        h8[j] = (short)h; l8[j] = (short)lo;
    }
    *(short8*)base = h8;
    *(short8*)(base + PANHALF) = l8;
}

// ---------------------------------------------------------------------------
// split_w: W[1024][2048] f32 -> transposed hi/lo bf16 panels, LDS transpose
// then flat-chunk coalesced writes. Grid (64, 16, 3).
// ---------------------------------------------------------------------------
__global__ __launch_bounds__(256)
void split_w(const float* __restrict__ Wq, const float* __restrict__ Wk,
             const float* __restrict__ Wv, unsigned short* __restrict__ Wpan)
{
    const int z = blockIdx.z;
    const float* W = (z == 0) ? Wq : (z == 1) ? Wk : Wv;
    char* pan = (char*)Wpan + (size_t)z * WPAN_Z_BYTES;

    __shared__ __align__(16) float T[64][36];
    const int t  = threadIdx.x;
    const int nt = blockIdx.x;   // n tiles of 32
    const int kt = blockIdx.y;   // k tiles of 64
    const int kk = t >> 3, cg = (t & 7) * 4;
#pragma unroll
    for (int i = 0; i < 2; ++i) {
        int kr = kk + i * 32;
        *(f32x4*)&T[kr][cg] = *(const f32x4*)(W + (size_t)(kt * 64 + kr) * TWOC + nt * 32 + cg);
    }
    __syncthreads();

    const int nbk = nt >> 2, nlb = (nt & 3) * 32;
#pragma unroll
    for (int i = 0; i < 2; ++i) {
        int c = t + i * 256;
        if (c < 320) {
            int ksi = (c >= 160) ? 1 : 0;
            int cc  = c - ksi * 160;
            int row = cc / 5, slot = cc - row * 5;
            char* base = pan + (size_t)(nbk * NPAN_K + kt * 2 + ksi) * PANPAIR
                       + (nlb + row) * 80 + slot * 16;
            short8 h8, l8;
            if (slot == 4) {
                h8 = (short8){0,0,0,0,0,0,0,0};
                l8 = h8;
            } else {
#pragma unroll
                for (int j = 0; j < 8; ++j) {
                    float xv = T[ksi * 32 + slot * 8 + j][row];
                    unsigned short h = bf16_rne(xv);
                    float hf = __uint_as_float((unsigned int)h << 16);
                    unsigned short lo = bf16_rne(xv - hf);
                    h8[j] = (short)h; l8[j] = (short)lo;
                }
            }
            *(short8*)base = h8;
            *(short8*)(base + PANHALF) = l8;
        }
    }
}

// ---------------------------------------------------------------------------
// mfma_gemm: Y = X @ W + bias (split-bf16), output [bh*2+part][n][d] f32.
// Unchanged (passed rounds 2-4).
// ---------------------------------------------------------------------------
__global__ __launch_bounds__(256)
void mfma_gemm(const unsigned short* __restrict__ Xpan,
               const unsigned short* __restrict__ Wpan,
               const float* __restrict__ Bq, const float* __restrict__ Bk,
               const float* __restrict__ Bv,
               float* __restrict__ Yq, float* __restrict__ Yk, float* __restrict__ Yv)
{
    __shared__ __align__(16) char AB[40960];
    const int t = threadIdx.x, l = t & 63, w = t >> 6;
    const int wm = w >> 1, wn = w & 1;
    const int nb = blockIdx.x, mb = blockIdx.y, z = blockIdx.z;
    const char* Apan = (const char*)Xpan + (size_t)mb * NPAN_K * PANPAIR;
    const char* Bpan = (const char*)Wpan + (size_t)z * WPAN_Z_BYTES
                                        + (size_t)nb * NPAN_K * PANPAIR;
    const float* bias = (z == 0) ? Bq : (z == 1) ? Bk : Bv;
    float* Y = (z == 0) ? Yq : (z == 1) ? Yk : Yv;

    f32x4 acc[4][4];
#pragma unroll
    for (int i = 0; i < 4; ++i)
#pragma unroll
        for (int j = 0; j < 4; ++j) acc[i][j] = (f32x4){0.f, 0.f, 0.f, 0.f};

    {
#pragma unroll
        for (int r = 0; r < 5; ++r) {
            int off = r * 4096 + t * 16;
            gload_lds16(Apan + off, AB + off);
            gload_lds16(Bpan + off, AB + 20480 + off);
        }
    }
    const int lg  = (l >> 4) * 16;
    const int l15 = l & 15;

    for (int ks = 0; ks < 32; ++ks) {
        __syncthreads();
        short8 ahi[4], alo[4];
#pragma unroll
        for (int fi = 0; fi < 4; ++fi) {
            int row = wm * 64 + fi * 16 + l15;
            ahi[fi] = *(const short8*)(AB + row * 80 + lg);
            alo[fi] = *(const short8*)(AB + PANHALF + row * 80 + lg);
        }
#pragma unroll
        for (int fj = 0; fj < 4; ++fj) {
            int rn = wn * 64 + fj * 16 + l15;
            short8 bh = *(const short8*)(AB + 20480 + rn * 80 + lg);
            short8 bl = *(const short8*)(AB + 30720 + rn * 80 + lg);
            bf16x8 bhv = __builtin_bit_cast(bf16x8, bh);
            bf16x8 blv = __builtin_bit_cast(bf16x8, bl);
#pragma unroll
            for (int fi = 0; fi < 4; ++fi) {
                bf16x8 ahv = __builtin_bit_cast(bf16x8, ahi[fi]);
                bf16x8 alv = __builtin_bit_cast(bf16x8, alo[fi]);
                acc[fi][fj] = __builtin_amdgcn_mfma_f32_16x16x32_bf16(ahv, bhv, acc[fi][fj], 0, 0, 0);
                acc[fi][fj] = __builtin_amdgcn_mfma_f32_16x16x32_bf16(ahv, blv, acc[fi][fj], 0, 0, 0);
                acc[fi][fj] = __builtin_amdgcn_mfma_f32_16x16x32_bf16(alv, bhv, acc[fi][fj], 0, 0, 0);
            }
        }
        __syncthreads();
        if (ks < 31) {
            const char* ga = Apan + (size_t)(ks + 1) * PANPAIR;
            const char* gb = Bpan + (size_t)(ks + 1) * PANPAIR;
#pragma unroll
            for (int r = 0; r < 5; ++r) {
                int off = r * 4096 + t * 16;
                gload_lds16(ga + off, AB + off);
                gload_lds16(gb + off, AB + 20480 + off);
            }
        }
    }

#pragma unroll
    for (int fj = 0; fj < 4; ++fj) {
        int ccol = nb * 128 + wn * 64 + fj * 16 + l15;
        float bb = bias[ccol];
        int hh = ccol >> 7, pp = (ccol >> 6) & 1, d0 = ccol & 63;
        float* ybase = Y + (size_t)(hh * 2 + pp) * NB + d0;
#pragma unroll
        for (int fi = 0; fi < 4; ++fi) {
            int mb4 = mb * 128 + wm * 64 + fi * 16 + (l >> 4) * 4;
#pragma unroll
            for (int r = 0; r < 4; ++r) {
                int mg = mb4 + r;
                int bidx = mg >> 10, n = mg & 1023;
                ybase[(size_t)(bidx * 32) * NB + n * 64] = acc[fi][fj][r] + bb;
            }
        }
    }
}

// ---------------------------------------------------------------------------
// ln_relu: LayerNorm+gamma/beta+ReLU; q,k -> bf16 hi/lo panels; v -> f32.
// Unchanged (passed rounds 3-4).
// ---------------------------------------------------------------------------
__global__ __launch_bounds__(256)
void ln_relu(float* __restrict__ Yq, float* __restrict__ Yk, float* __restrict__ Yv,
             const float* __restrict__ Gq, const float* __restrict__ BTq,
             const float* __restrict__ Gk, const float* __restrict__ BTk,
             const float* __restrict__ Gv, const float* __restrict__ BTv,
             unsigned short* __restrict__ Qpan, unsigned short* __restrict__ Kpan)
{
    float* Y; const float* G; const float* Bt;
    if (blockIdx.y == 0)      { Y = Yq; G = Gq; Bt = BTq; }
    else if (blockIdx.y == 1) { Y = Yk; G = Gk; Bt = BTk; }
    else                      { Y = Yv; G = Gv; Bt = BTv; }

    const int r    = blockIdx.x;
    const int bidx = r >> 10;
    const int n    = r & 1023;
    const int t    = threadIdx.x;
    const int e0   = t * 8;
    const int chunk = e0 >> 6;
    const int d     = e0 & 63;

    float* p = Y + (size_t)(bidx * 32 + chunk) * NB + n * 64 + d;
    f32x4 v0 = *(f32x4*)p;
    f32x4 v1 = *(f32x4*)(p + 4);
    float xv[8] = {v0[0],v0[1],v0[2],v0[3],v1[0],v1[1],v1[2],v1[3]};

    __shared__ float red[8];
    float s = 0.f;
#pragma unroll
    for (int j = 0; j < 8; ++j) s += xv[j];
#pragma unroll
    for (int off = 32; off > 0; off >>= 1) s += __shfl_down(s, off);
    const int lane = t & 63, wid = t >> 6;
    if (lane == 0) red[wid] = s;
    __syncthreads();
    const float mean = (red[0] + red[1] + red[2] + red[3]) * (1.f / 2048.f);
    __syncthreads();

    float sq = 0.f;
#pragma unroll
    for (int j = 0; j < 8; ++j) { float dx = xv[j] - mean; sq += dx * dx; }
#pragma unroll
    for (int off = 32; off > 0; off >>= 1) sq += __shfl_down(sq, off);
    if (lane == 0) red[wid] = sq;
    __syncthreads();
    const float var  = (red[0] + red[1] + red[2] + red[3]) * (1.f / 2048.f);
    const float rstd = 1.f / sqrtf(var + 1e-5f);

    float yv[8];
#pragma unroll
    for (int j = 0; j < 8; ++j)
        yv[j] = fmaxf((xv[j] - mean) * rstd * G[e0 + j] + Bt[e0 + j], 0.f);

    if (blockIdx.y == 2) {
        f32x4 o0, o1;
#pragma unroll
        for (int j = 0; j < 4; ++j) { o0[j] = yv[j]; o1[j] = yv[j + 4]; }
        *(f32x4*)p       = o0;
        *(f32x4*)(p + 4) = o1;
        return;
    }

    short8 h8, l8;
#pragma unroll
    for (int j = 0; j < 8; ++j) {
        unsigned short hh = bf16_rne(yv[j]);
        float hf = __uint_as_float((unsigned int)hh << 16);
        unsigned short lo = bf16_rne(yv[j] - hf);
        h8[j] = (short)hh; l8[j] = (short)lo;
    }
    const int bh   = bidx * 16 + (e0 >> 7);
    const int dim0 = e0 & 127;
    if (blockIdx.y == 0) {
        unsigned short* dst = Qpan + ((size_t)(bh * 2) * 1024 + n) * 128 + dim0;
        *(short8*)dst = h8;
        *(short8*)(dst + QPLANE) = l8;
    } else {
        unsigned short* dst = Kpan + ((size_t)(bh * 2) * 1024 + n) * 136 + dim0;
        *(short8*)dst = h8;
        *(short8*)(dst + (size_t)1024 * 136) = l8;
    }
}

// ---------------------------------------------------------------------------
// vsplit: vbuf f32 [bh*2+part][n][64] -> Vt fp16 [bh][d2(128)][n(1024)].
// Unchanged (passed round 4).
// ---------------------------------------------------------------------------
__global__ __launch_bounds__(256)
void vsplit(const float* __restrict__ vbuf, unsigned short* __restrict__ Vt)
{
    __shared__ __align__(16) unsigned short Tb[128][72];   // pitch 144 B
    const int bh = blockIdx.x, nt = blockIdx.y;
    const int n0 = nt * 64;
    const int t = threadIdx.x;
    {
        const int p = t >> 7, u = t & 127, l4 = u & 3, nl0 = u >> 2;
        const float* src0 = vbuf + (size_t)(bh * 2 + p) * NB + (size_t)n0 * 64 + l4 * 16;
#pragma unroll
        for (int rep = 0; rep < 2; ++rep) {
            const int row = nl0 + rep * 32;
            const float* sp = src0 + (size_t)row * 64;
            f32x4 a = *(const f32x4*)sp,       b = *(const f32x4*)(sp + 4);
            f32x4 c = *(const f32x4*)(sp + 8), d = *(const f32x4*)(sp + 12);
            float vv[16] = {a[0],a[1],a[2],a[3],b[0],b[1],b[2],b[3],
                            c[0],c[1],c[2],c[3],d[0],d[1],d[2],d[3]};
#pragma unroll
            for (int j = 0; j < 16; ++j)
                Tb[p * 64 + l4 * 16 + j][row] =
                    __builtin_bit_cast(unsigned short, (_Float16)vv[j]);
        }
    }
    __syncthreads();
    const int d2 = t >> 1, sseg = t & 1;
    unsigned short* dst = Vt + ((size_t)bh * 128 + d2) * 1024 + n0 + sseg * 32;
#pragma unroll
    for (int i = 0; i < 4; ++i)
        *(short8*)(dst + i * 8) = *(const short8*)&Tb[d2][sseg * 32 + i * 8];
}

// ---------------------------------------------------------------------------
// attn staging helpers (flat-chunk global_load_lds; lane-linear LDS dest).
// ---------------------------------------------------------------------------
__device__ __forceinline__ void stage_K(const char* kplane, int kt, char* dst, int t) {
#pragma unroll
    for (int i = 0; i < 4; ++i) {
        int c = t + i * 256;
        int hf = (c >= 544) ? 1 : 0;
        int rem = c - hf * 544;
        gload_lds16(kplane + (size_t)hf * KPLANEB + (size_t)kt * 8704 + rem * 16,
                    dst + c * 16);
    }
    if (t < 64) {
        int c = 1024 + t;
        gload_lds16(kplane + KPLANEB + (size_t)kt * 8704 + (c - 544) * 16,
                    dst + c * 16);
    }
}

__device__ __forceinline__ void stage_V(const char* vplane, int kt, char* dst, int t) {
#pragma unroll
    for (int i = 0; i < 2; ++i) {
        int c = t + i * 256;
        int r = c / 5, s = c - r * 5; if (s == 4) s = 3;
        gload_lds16(vplane + (size_t)r * 2048 + kt * 64 + s * 16, dst + c * 16);
    }
    if (t < 128) {
        int c = 512 + t;
        int r = c / 5, s = c - r * 5; if (s == 4) s = 3;
        gload_lds16(vplane + (size_t)r * 2048 + kt * 64 + s * 16, dst + c * 16);
    }
}

// ---------------------------------------------------------------------------
// attn_mfma: MFMA flash attention, swapped S^T = K @ Q^T.
// Round 5: native v_sin/v_cos/v_exp2 scores (log2-domain softmax), defer-max
// (THR=10 log2 units), NO mid barrier (P/sc are wave-private; V double-buffered
// and stable since top sync). Grid 512 (XCD-swizzled), 256 threads.
// ---------------------------------------------------------------------------
__global__ __launch_bounds__(256)
void attn_mfma(const unsigned short* __restrict__ Qpan,
               const unsigned short* __restrict__ Kpan,
               const unsigned short* __restrict__ Vtpan,
               const float* __restrict__ amp_mix, const float* __restrict__ phase_mix,
               float* __restrict__ Out)
{
    __shared__ __align__(16) char Klds[2][17408];   // [hi 8704][lo 8704]
    __shared__ __align__(16) char Vlds[2][10240];   // 128 rows x 80 B
    __shared__ __align__(16) char Plds[5120];       // 64 q rows x 80 B (fp16)
    __shared__ float sc_s[64];
    __shared__ float l_s[64];

    const int bid = blockIdx.x;
    const int swz = (bid & 7) * 64 + (bid >> 3);      // XCD-chunked
    const int bh = swz >> 4, qt = swz & 15;
    const int h = bh & 15, bidx = bh >> 4;

    const int t = threadIdx.x, l = t & 63, w = t >> 6;
    const int l15 = l & 15, g = l >> 4;

    const float amix = amp_mix[h], pmix = phase_mix[h];
    const float L2E = 1.44269504f;
    const float INV2PI = 0.15915493667f;

    // persistent Q fragments (B-operand of S^T)
    bf16x8 Qf[2][4];
    {
        const unsigned short* qb = Qpan
            + ((size_t)(bh * 2) * 1024 + qt * 64 + w * 16 + l15) * 128 + g * 8;
#pragma unroll
        for (int hf = 0; hf < 2; ++hf)
#pragma unroll
            for (int db = 0; db < 4; ++db)
                Qf[hf][db] = __builtin_bit_cast(bf16x8,
                    *(const short8*)(qb + (size_t)hf * QPLANE + db * 32));
    }

    const char* kbase = (const char*)Kpan + (size_t)(bh * 2) * KPLANEB;
    const char* vbase = (const char*)Vtpan + (size_t)bh * VPLANEB;

    f32x4 O[8];
#pragma unroll
    for (int i = 0; i < 8; ++i) O[i] = (f32x4){0.f, 0.f, 0.f, 0.f};
    float m_ = -1e30f, l_ = 0.f;

    // prologue: stage tile 0 into buffer 0
    stage_K(kbase, 0, Klds[0], t);
    stage_V(vbase, 0, Vlds[0], t);

    for (int kt = 0; kt < 32; ++kt) {
        __syncthreads();                 // drains vmcnt -> buf[kt&1] ready
        const int buf = kt & 1;
        if (kt < 31) {                   // prefetch kt+1 (hidden across full iter)
            stage_K(kbase, kt + 1, Klds[buf ^ 1], t);
            stage_V(vbase, kt + 1, Vlds[buf ^ 1], t);
        }
        const char* Kb = Klds[buf];

        // ----- S^T phase -----
        f32x4 aA[2], pA[2];
        __builtin_amdgcn_s_setprio(1);
#pragma unroll
        for (int fi = 0; fi < 2; ++fi) {
            aA[fi] = (f32x4){0.f, 0.f, 0.f, 0.f};
            pA[fi] = (f32x4){0.f, 0.f, 0.f, 0.f};
            const char* kr = Kb + (fi * 16 + l15) * 272 + g * 16;
            bf16x8 Fh[4], Fl[4];
#pragma unroll
            for (int db = 0; db < 4; ++db) {
                Fh[db] = __builtin_bit_cast(bf16x8, *(const short8*)(kr + db * 64));
                Fl[db] = __builtin_bit_cast(bf16x8, *(const short8*)(kr + 8704 + db * 64));
            }
            bf16x8 Nh[2] = { bneg(Fh[2]), bneg(Fh[3]) };
            bf16x8 Nl[2] = { bneg(Fl[2]), bneg(Fl[3]) };
#pragma unroll
            for (int db = 0; db < 4; ++db) {
                bf16x8 Ah = (db < 2) ? Fh[db] : Nh[db - 2];
                bf16x8 Al = (db < 2) ? Fl[db] : Nl[db - 2];
                aA[fi] = __builtin_amdgcn_mfma_f32_16x16x32_bf16(Ah, Qf[0][db], aA[fi], 0, 0, 0);
                aA[fi] = __builtin_amdgcn_mfma_f32_16x16x32_bf16(Ah, Qf[1][db], aA[fi], 0, 0, 0);
                aA[fi] = __builtin_amdgcn_mfma_f32_16x16x32_bf16(Al, Qf[0][db], aA[fi], 0, 0, 0);
                bf16x8 Ph = Fh[db ^ 2];
                bf16x8 Pl = Fl[db ^ 2];
                pA[fi] = __builtin_amdgcn_mfma_f32_16x16x32_bf16(Ph, Qf[0][db], pA[fi], 0, 0, 0);
                pA[fi] = __builtin_amdgcn_mfma_f32_16x16x32_bf16(Ph, Qf[1][db], pA[fi], 0, 0, 0);
                pA[fi] = __builtin_amdgcn_mfma_f32_16x16x32_bf16(Pl, Qf[0][db], pA[fi], 0, 0, 0);
            }
        }
        __builtin_amdgcn_s_setprio(0);

        // ----- scores (native trans; sv in log2 domain) -----
        float sv[2][4];
#pragma unroll
        for (int fi = 0; fi < 2; ++fi)
#pragma unroll
            for (int r = 0; r < 4; ++r) {
                float amp = aA[fi][r] * amix;
                float ph  = pA[fi][r] * pmix;
                float rev = ph * INV2PI;
                rev = rev - floorf(rev);               // -> v_fract
                float sn = __builtin_amdgcn_sinf(rev); // sin(2*pi*rev)
                float cs = __builtin_amdgcn_cosf(rev);
                float e  = __builtin_amdgcn_exp2f(amp * sn * -L2E);
                float sig = __builtin_amdgcn_rcpf(1.f + e);
                sv[fi][r] = amp * cs * sig * L2E;      // log2-domain score
            }

        // ----- online softmax (log2 domain; defer-max THR=10) -----
        float rm = sv[0][0];
#pragma unroll
        for (int fi = 0; fi < 2; ++fi)
#pragma unroll
            for (int r = 0; r < 4; ++r) rm = fmaxf(rm, sv[fi][r]);
        rm = fmaxf(rm, __shfl_xor(rm, 16));
        rm = fmaxf(rm, __shfl_xor(rm, 32));
        const bool upd = (rm > m_ + 10.f);
        const float mn  = upd ? rm : m_;
        const float scl = upd ? __builtin_amdgcn_exp2f(m_ - mn) : 1.f;
        float pv[2][4];
        float rs = 0.f;
#pragma unroll
        for (int fi = 0; fi < 2; ++fi)
#pragma unroll
            for (int r = 0; r < 4; ++r) {
                pv[fi][r] = __builtin_amdgcn_exp2f(sv[fi][r] - mn);
                rs += pv[fi][r];
            }
        rs += __shfl_xor(rs, 16);
        rs += __shfl_xor(rs, 32);
        l_ = l_ * scl + rs;
        m_ = mn;
        const bool anyscale = __any(upd);

#pragma unroll
        for (int fi = 0; fi < 2; ++fi) {
            short4v pk;
#pragma unroll
            for (int r = 0; r < 4; ++r)
                pk[r] = (short)__builtin_bit_cast(unsigned short, (_Float16)pv[fi][r]);
            *(short4v*)(Plds + (w * 16 + l15) * 80 + fi * 32 + g * 8) = pk;
        }
        if (g == 0) sc_s[w * 16 + l15] = scl;
        // No barrier: Plds rows & sc_s entries are wave-private; Vlds[buf]
        // stable since top sync. Compiler inserts lgkmcnt for the WAR/RAW.

        // ----- PV phase (fp16) -----
        if (anyscale) {
            f32x4 scv;
#pragma unroll
            for (int r = 0; r < 4; ++r) scv[r] = sc_s[w * 16 + g * 4 + r];
#pragma unroll
            for (int nt = 0; nt < 8; ++nt) O[nt] *= scv;
        }
        half8 Pf = __builtin_bit_cast(half8,
            *(const short8*)(Plds + (w * 16 + l15) * 80 + g * 16));
        const char* Vb = Vlds[buf];
        __builtin_amdgcn_s_setprio(1);
#pragma unroll
        for (int nt = 0; nt < 8; ++nt) {
            half8 Vh = __builtin_bit_cast(half8,
                *(const short8*)(Vb + (nt * 16 + l15) * 80 + g * 16));
            O[nt] = __builtin_amdgcn_mfma_f32_16x16x32_f16(Pf, Vh, O[nt], 0, 0, 0);
        }
        __builtin_amdgcn_s_setprio(0);
    }

    // ----- epilogue -----
    if (g == 0) l_s[w * 16 + l15] = l_;
    __syncthreads();
    f32x4 invv;
#pragma unroll
    for (int r = 0; r < 4; ++r) invv[r] = __builtin_amdgcn_rcpf(l_s[w * 16 + g * 4 + r]);
#pragma unroll
    for (int nt = 0; nt < 8; ++nt) {
#pragma unroll
        for (int r = 0; r < 4; ++r) {
            const int n = qt * 64 + w * 16 + g * 4 + r;
            Out[(size_t)(bidx * NSEQ + n) * TWOC + h * 128 + nt * 16 + l15] = O[nt][r] * invv[r];
        }
    }
}

// ---------------------------------------------------------------------------
extern "C" void kernel_launch(void* const* d_in, const int* in_sizes, int n_in,
                              void* d_out, int out_size, void* d_ws, size_t ws_size,
                              hipStream_t stream) {
    (void)in_sizes; (void)n_in; (void)out_size; (void)ws_size;
    const float* x      = (const float*)d_in[0];
    const float* q_w    = (const float*)d_in[1];
    const float* q_b    = (const float*)d_in[2];
    const float* q_g    = (const float*)d_in[3];
    const float* q_beta = (const float*)d_in[4];
    const float* k_w    = (const float*)d_in[5];
    const float* k_b    = (const float*)d_in[6];
    const float* k_g    = (const float*)d_in[7];
    const float* k_beta = (const float*)d_in[8];
    const float* v_w    = (const float*)d_in[9];
    const float* v_b    = (const float*)d_in[10];
    const float* v_g    = (const float*)d_in[11];
    const float* v_beta = (const float*)d_in[12];
    const float* amp_mix   = (const float*)d_in[13];
    const float* phase_mix = (const float*)d_in[14];

    char* ws = (char*)d_ws;
    unsigned short* Qpan  = (unsigned short*)(ws + QPAN_OFF);
    unsigned short* Kpan  = (unsigned short*)(ws + KPAN_OFF);
    unsigned short* Vtpan = (unsigned short*)(ws + VTPAN_OFF);
    unsigned short* Wpan  = (unsigned short*)(ws + QPAN_OFF);   // dead after gemm
    float* qbuf = (float*)(ws + QBUF_OFF);
    float* kbuf = (float*)(ws + KBUF_OFF);
    float* vbuf = (float*)(ws + VBUF_OFF);
    unsigned short* Xpan = (unsigned short*)d_out;   // scratch until attn writes

    split_x<<<1280, 256, 0, stream>>>(x, Xpan);
    split_w<<<dim3(64, 16, 3), 256, 0, stream>>>(q_w, k_w, v_w, Wpan);
    mfma_gemm<<<dim3(16, 16, 3), 256, 0, stream>>>(
        Xpan, Wpan, q_b, k_b, v_b, qbuf, kbuf, vbuf);
    ln_relu<<<dim3(2048, 3), 256, 0, stream>>>(
        qbuf, kbuf, vbuf, q_g, q_beta, k_g, k_beta, v_g, v_beta, Qpan, Kpan);
    vsplit<<<dim3(32, 16), 256, 0, stream>>>(vbuf, Vtpan);
    attn_mfma<<<512, 256, 0, stream>>>(
        Qpan, Kpan, Vtpan, amp_mix, phase_mix, (float*)d_out);
}